// Round 1
// baseline (29180.756 us; speedup 1.0000x reference)
//
#include <hip/hip_runtime.h>
#include <hip/hip_bf16.h>

#define Bn 8
#define Hh 256
#define Ww 256
#define HW 65536
#define SDIM 64
#define LABELS 35
#define NHID 128
#define TW 258                     // Ww + 2 halo
#define CHUNK 4                    // input channels per stage
#define CELEMS (CHUNK * 3 * TW)    // 3096 floats per chunk stage
#define PREG 13                    // ceil(CELEMS / 256)

static inline __device__ float b2f(__hip_bfloat16 x) { return __bfloat162float(x); }

// ---------------- weight prep: f32 [O][I][9] -> f32 [O][ICP][9], ic zero-pad
__global__ void prep_w(const float* __restrict__ src, float* __restrict__ dst,
                       int OC, int IC, int ICP) {
    int n = OC * ICP * 9;
    for (int idx = blockIdx.x * blockDim.x + threadIdx.x; idx < n; idx += gridDim.x * blockDim.x) {
        int oc = idx / (ICP * 9);
        int r  = idx % (ICP * 9);
        int ic = r / 9;
        int k  = r % 9;
        float v = 0.f;
        if (ic < IC) v = src[(oc * IC + ic) * 9 + k];
        dst[idx] = v;
    }
}

// ============================================================================
// Generic conv row engine: one output row (256 px) per block, 16 oc per acc set.
// 4-ic chunks, double-buffered LDS, global->reg prefetch of chunk c+1 issued
// BEFORE the FMA block of chunk c (latency hides under 1152-2304 FMAs),
// ds_write after compute, ONE barrier per chunk.
// ============================================================================
template <int ICTOT, int NACC, class LoadF>
__device__ __forceinline__ void conv_rows(
    float (&tile)[2][CHUNK][3 * TW],
    LoadF loadf,                           // (gic, rem) -> float, rem in [0, 3*TW)
    const float* const (&wb)[NACC],        // each pre-offset by ocb*ICTOT*9
    float (&acc)[NACC][16],
    int t)
{
    float pre[PREG];
    // stage chunk 0
#pragma unroll
    for (int j = 0; j < PREG; j++) {
        int i = t + j * 256;
        if (i < CELEMS) pre[j] = loadf(i / (3 * TW), i % (3 * TW));
    }
#pragma unroll
    for (int j = 0; j < PREG; j++) {
        int i = t + j * 256;
        if (i < CELEMS) (&tile[0][0][0])[i] = pre[j];
    }
    __syncthreads();

    int nb = 0;
    for (int icc = 0; icc < ICTOT; icc += CHUNK) {
        const bool has = (icc + CHUNK) < ICTOT;
        if (has) {   // issue next-chunk global loads early (T14 async-STAGE)
#pragma unroll
            for (int j = 0; j < PREG; j++) {
                int i = t + j * 256;
                if (i < CELEMS) pre[j] = loadf(icc + CHUNK + i / (3 * TW), i % (3 * TW));
            }
        }
        // compute current chunk
#pragma unroll
        for (int ic = 0; ic < CHUNK; ic++) {
            float v[9];
#pragma unroll
            for (int ky = 0; ky < 3; ky++)
#pragma unroll
                for (int kx = 0; kx < 3; kx++)
                    v[ky * 3 + kx] = tile[nb][ic][ky * TW + t + kx];
#pragma unroll
            for (int a = 0; a < NACC; a++) {
#pragma unroll
                for (int oc = 0; oc < 16; oc++) {
                    const float* wp = wb[a] + ((size_t)oc * ICTOT + icc + ic) * 9;
#pragma unroll
                    for (int k = 0; k < 9; k++) acc[a][oc] = fmaf(v[k], wp[k], acc[a][oc]);
                }
            }
        }
        if (has) {   // write-late into the other buffer (free since prev sync)
#pragma unroll
            for (int j = 0; j < PREG; j++) {
                int i = t + j * 256;
                if (i < CELEMS) (&tile[nb ^ 1][0][0])[i] = pre[j];
            }
        }
        __syncthreads();
        nb ^= 1;
    }
}

// ---------------- fused: conv1(64->64,lrelu)+masked pooling AND conv_c0 stats
__global__ __launch_bounds__(256, 4) void conv1c0_kernel(
    const float* __restrict__ in,             // [B][64][H][W]
    const float* __restrict__ w1, const float* __restrict__ b1,   // conv1
    const float* __restrict__ w0, const float* __restrict__ b0,   // conv_c0
    const int* __restrict__ seg, const float* __restrict__ bg,
    const float* __restrict__ mask,
    float* __restrict__ sums, int* __restrict__ cnts, float* __restrict__ statacc)
{
    __shared__ float tile[2][CHUNK][3 * TW];
    __shared__ float s35[LABELS * 16];
    __shared__ int   c35[LABELS];
    __shared__ float wsum[4][16][2];

    const int t = threadIdx.x, h = blockIdx.y, b = blockIdx.z, ocb = blockIdx.x * 16;
    for (int i = t; i < LABELS * 16; i += 256) s35[i] = 0.f;
    if (t < LABELS) c35[t] = 0;

    float acc[2][16];
#pragma unroll
    for (int i = 0; i < 16; i++) { acc[0][i] = b1[ocb + i]; acc[1][i] = b0[ocb + i]; }

    const float* inb = in + (size_t)b * 64 * HW;
    const float* wb[2] = { w1 + (size_t)ocb * 64 * 9, w0 + (size_t)ocb * 64 * 9 };
    auto loadf = [&](int gic, int rem) -> float {
        int r = rem / TW, x = rem - r * TW;
        int gh = h + r - 1, gw = x - 1;
        float v = 0.f;
        if ((unsigned)gh < Hh && (unsigned)gw < Ww) v = inb[(size_t)gic * HW + gh * Ww + gw];
        return v;
    };
    conv_rows<64, 2>(tile, loadf, wb, acc, t);

    // --- conv1 branch: lrelu + masked class pooling
    int p = h * Ww + t;
    int lab = seg[(size_t)b * HW + p];
    bool m = (bg[(size_t)b * HW + p] != 0.f) && (mask[(size_t)b * HW + p] == 0.f);
    if (m) {
#pragma unroll
        for (int oc = 0; oc < 16; oc++) {
            float o = acc[0][oc];
            o = (o >= 0.f) ? o : 0.2f * o;
            atomicAdd(&s35[lab * 16 + oc], o);
        }
        if (blockIdx.x == 0) atomicAdd(&c35[lab], 1);
    }
    // --- conv_c0 branch: per-channel sum / sumsq
    int lane = t & 63, w = t >> 6;
#pragma unroll
    for (int oc = 0; oc < 16; oc++) {
        float s = acc[1][oc], ss = acc[1][oc] * acc[1][oc];
#pragma unroll
        for (int off = 32; off > 0; off >>= 1) { s += __shfl_down(s, off); ss += __shfl_down(ss, off); }
        if (lane == 0) { wsum[w][oc][0] = s; wsum[w][oc][1] = ss; }
    }
    __syncthreads();
    for (int i = t; i < LABELS * 16; i += 256) {
        float v = s35[i];
        if (v != 0.f) {
            int s = i >> 4, oc = i & 15;
            atomicAdd(&sums[((size_t)b * LABELS + s) * SDIM + ocb + oc], v);
        }
    }
    if (blockIdx.x == 0 && t < LABELS && c35[t] > 0) atomicAdd(&cnts[b * LABELS + t], c35[t]);
    if (t < 16) {
        float S = 0.f, SS = 0.f;
#pragma unroll
        for (int w2 = 0; w2 < 4; w2++) { S += wsum[w2][t][0]; SS += wsum[w2][t][1]; }
        atomicAdd(&statacc[(size_t)(b * SDIM + ocb + t) * 2 + 0], S);
        atomicAdd(&statacc[(size_t)(b * SDIM + ocb + t) * 2 + 1], SS);
    }
}

// ---------------- codes = keep * where(cnt>0, sums/cnt, 0) ------------------
__global__ void codes_kernel(const float* __restrict__ sums, const int* __restrict__ cnts,
                             float* __restrict__ codes) {
    int idx = blockIdx.x * blockDim.x + threadIdx.x;
    if (idx >= Bn * LABELS * SDIM) return;
    int s  = (idx >> 6) % LABELS;
    int bs = idx >> 6;
    int cnt = cnts[bs];
    bool keep = !(s >= 24 && s <= 33);
    codes[idx] = (cnt > 0 && keep) ? sums[idx] / (float)cnt : 0.f;
}

__global__ void finalize_stats(const float* __restrict__ statacc,
                               float* __restrict__ mu, float* __restrict__ rsig) {
    int i = blockIdx.x * blockDim.x + threadIdx.x;
    if (i >= Bn * SDIM) return;
    float S = statacc[2 * i], SS = statacc[2 * i + 1];
    float m = S / (float)HW;
    float v = SS / (float)HW - m * m;
    mu[i] = m;
    rsig[i] = rsqrtf(v + 1e-5f);
}

// ---------------- conv_sh with out_map generated on the fly -----------------
// channels: 0..63 style (codes[lab][f]*bg), 64..98 one-hot*bg, 99 zero (pad)
__global__ __launch_bounds__(256, 4) void conv_sh_kernel(
    const int* __restrict__ seg, const float* __restrict__ bg,
    const float* __restrict__ codes,          // [B][35][64]
    const float* __restrict__ wf,             // [128][100][9]
    const float* __restrict__ bf,             // [128]
    __hip_bfloat16* __restrict__ actv,        // [Z][128][HW]
    int b0, int abstride)
{
    __shared__ float tile[2][CHUNK][3 * TW];
    __shared__ float cod[LABELS * 65];        // stride 65: bank-conflict-free lab lookup
    __shared__ int   labrow[3 * TW];
    __shared__ float bgrow[3 * TW];

    const int t = threadIdx.x, h = blockIdx.y, ocb = blockIdx.x * 16;
    const int b = b0 + blockIdx.z;
    const int*   seg_b   = seg + (size_t)b * HW;
    const float* bg_b    = bg + (size_t)b * HW;
    const float* codes_b = codes + (size_t)b * LABELS * SDIM;
    __hip_bfloat16* actv_b = actv + (size_t)blockIdx.z * abstride;

    for (int i = t; i < LABELS * SDIM; i += 256) cod[(i >> 6) * 65 + (i & 63)] = codes_b[i];
    for (int i = t; i < 3 * TW; i += 256) {
        int r = i / TW, x = i - r * TW;
        int gh = h + r - 1, gw = x - 1;
        int lab = 0; float bgv = 0.f;
        if ((unsigned)gh < Hh && (unsigned)gw < Ww) { lab = seg_b[gh * Ww + gw]; bgv = bg_b[gh * Ww + gw]; }
        labrow[i] = lab; bgrow[i] = bgv;
    }
    float acc[1][16];
#pragma unroll
    for (int i = 0; i < 16; i++) acc[0][i] = bf[ocb + i];
    __syncthreads();

    const float* wb[1] = { wf + (size_t)ocb * 100 * 9 };
    auto loadf = [&](int gic, int rem) -> float {
        int lab = labrow[rem]; float bgv = bgrow[rem];
        float v;
        if (gic < 64)      v = cod[lab * 65 + gic] * bgv;
        else if (gic < 99) v = ((gic - 64) == lab) ? bgv : 0.f;
        else               v = 0.f;
        return v;
    };
    conv_rows<100, 1>(tile, loadf, wb, acc, t);

#pragma unroll
    for (int oc = 0; oc < 16; oc++) {
        float o = fmaxf(acc[0][oc], 0.f);   // relu
        actv_b[(size_t)(ocb + oc) * HW + h * Ww + t] = __float2bfloat16(o);
    }
}

// ---------------- fused: dx=conv_c0, gamma/beta convs, IN + lrelu -----------
__global__ __launch_bounds__(256, 4) void final_fused_kernel(
    const float* __restrict__ fin,              // [B][64][HW]
    const __hip_bfloat16* __restrict__ actv,    // [Z][128][HW]
    const float* __restrict__ wc0, const float* __restrict__ bc0,
    const float* __restrict__ wg,  const float* __restrict__ bg2,
    const float* __restrict__ wb2, const float* __restrict__ bb2,
    const float* __restrict__ mu, const float* __restrict__ rsig,
    float* __restrict__ out, int b0, int abstride)
{
    __shared__ float tile[2][CHUNK][3 * TW];
    const int t = threadIdx.x, h = blockIdx.y, ocb = blockIdx.x * 16;
    const int b = b0 + blockIdx.z;
    const float* fin_b = fin + (size_t)b * 64 * HW;
    const __hip_bfloat16* actv_b = actv + (size_t)blockIdx.z * abstride;

    // pass 1: dx = conv_c0(featmap_in)
    float accd[1][16];
#pragma unroll
    for (int i = 0; i < 16; i++) accd[0][i] = bc0[ocb + i];
    const float* wbd[1] = { wc0 + (size_t)ocb * 64 * 9 };
    auto loadf1 = [&](int gic, int rem) -> float {
        int r = rem / TW, x = rem - r * TW;
        int gh = h + r - 1, gw = x - 1;
        float v = 0.f;
        if ((unsigned)gh < Hh && (unsigned)gw < Ww) v = fin_b[(size_t)gic * HW + gh * Ww + gw];
        return v;
    };
    conv_rows<64, 1>(tile, loadf1, wbd, accd, t);

    // pass 2: gamma/beta convs over actv (two acc sets share one staging)
    float accgb[2][16];
#pragma unroll
    for (int i = 0; i < 16; i++) { accgb[0][i] = bg2[ocb + i]; accgb[1][i] = bb2[ocb + i]; }
    const float* wbgb[2] = { wg + (size_t)ocb * 128 * 9, wb2 + (size_t)ocb * 128 * 9 };
    auto loadf2 = [&](int gic, int rem) -> float {
        int r = rem / TW, x = rem - r * TW;
        int gh = h + r - 1, gw = x - 1;
        float v = 0.f;
        if ((unsigned)gh < Hh && (unsigned)gw < Ww) v = b2f(actv_b[(size_t)gic * HW + gh * Ww + gw]);
        return v;
    };
    conv_rows<128, 2>(tile, loadf2, wbgb, accgb, t);

    const float* mu_b = mu + b * SDIM;
    const float* rs_b = rsig + b * SDIM;
    float* out_b = out + (size_t)b * SDIM * HW;
#pragma unroll
    for (int oc = 0; oc < 16; oc++) {
        int c = ocb + oc;
        float nrm = (accd[0][oc] - mu_b[c]) * rs_b[c];
        float o = nrm * (1.f + accgb[0][oc]) + accgb[1][oc];
        o = (o >= 0.f) ? o : 0.2f * o;
        out_b[(size_t)c * HW + h * Ww + t] = o;
    }
}

// ===========================================================================
extern "C" void kernel_launch(void* const* d_in, const int* in_sizes, int n_in,
                              void* d_out, int out_size, void* d_ws, size_t ws_size,
                              hipStream_t stream) {
    const float* featmap_in = (const float*)d_in[0];
    const int*   seg        = (const int*)d_in[1];
    const float* bg         = (const float*)d_in[2];
    const float* mask       = (const float*)d_in[3];
    const float* w_conv     = (const float*)d_in[4];
    const float* b_conv     = (const float*)d_in[5];
    const float* w_c0       = (const float*)d_in[6];
    const float* b_c0       = (const float*)d_in[7];
    const float* w_sh       = (const float*)d_in[8];
    const float* b_sh       = (const float*)d_in[9];
    const float* w_g        = (const float*)d_in[10];
    const float* b_g        = (const float*)d_in[11];
    const float* w_b        = (const float*)d_in[12];
    const float* b_b        = (const float*)d_in[13];
    float* out = (float*)d_out;

    // ---- workspace arena ----
    char* ws = (char*)d_ws;
    size_t o = 0;
    auto alloc = [&](size_t bytes) -> char* {
        size_t r = o; o = (o + bytes + 255) & ~(size_t)255; return ws + r;
    };
    float* wf_sh   = (float*)alloc((size_t)128 * 100 * 9 * 4);
    float* sums    = (float*)alloc((size_t)Bn * LABELS * SDIM * 4);
    int*   cnts    = (int*)alloc((size_t)Bn * LABELS * 4);
    float* codes   = (float*)alloc((size_t)Bn * LABELS * SDIM * 4);
    float* statacc = (float*)alloc((size_t)Bn * SDIM * 2 * 4);
    float* mu      = (float*)alloc((size_t)Bn * SDIM * 4);
    float* rsig    = (float*)alloc((size_t)Bn * SDIM * 4);
    size_t actv_full = (size_t)Bn * NHID * HW * 2;       // 134 MB (bf16, all batches)
    size_t actv_one  = (size_t)NHID * HW * 2;            // 16.8 MB
    bool batched = (ws_size > o) && ((ws_size - o) >= actv_full + 512);
    __hip_bfloat16* actv = (__hip_bfloat16*)alloc(batched ? actv_full : actv_one);

    // ---- weight prep: only w_sh needs ic zero-padding (99 -> 100) ----
    prep_w<<<450, 256, 0, stream>>>(w_sh, wf_sh, 128, 99, 100);

    hipMemsetAsync(sums, 0, (size_t)Bn * LABELS * SDIM * 4, stream);
    hipMemsetAsync(cnts, 0, (size_t)Bn * LABELS * 4, stream);
    hipMemsetAsync(statacc, 0, (size_t)Bn * SDIM * 2 * 4, stream);

    // ---- fused conv1+pool AND conv_c0 stats (one staging pass) ----
    conv1c0_kernel<<<dim3(4, Hh, Bn), 256, 0, stream>>>(
        featmap_in, w_conv, b_conv, w_c0, b_c0, seg, bg, mask, sums, cnts, statacc);
    codes_kernel<<<(Bn * LABELS * SDIM + 255) / 256, 256, 0, stream>>>(sums, cnts, codes);
    finalize_stats<<<2, 256, 0, stream>>>(statacc, mu, rsig);

    if (batched) {
        // all batches in one launch each: 16384 / 8192 blocks -> full residency
        conv_sh_kernel<<<dim3(8, Hh, Bn), 256, 0, stream>>>(
            seg, bg, codes, wf_sh, b_sh, actv, 0, NHID * HW);
        final_fused_kernel<<<dim3(4, Hh, Bn), 256, 0, stream>>>(
            featmap_in, actv, w_c0, b_c0, w_g, b_g, w_b, b_b, mu, rsig, out, 0, NHID * HW);
    } else {
        // workspace too small for batched actv: per-batch fallback
        for (int b = 0; b < Bn; b++) {
            conv_sh_kernel<<<dim3(8, Hh, 1), 256, 0, stream>>>(
                seg, bg, codes, wf_sh, b_sh, actv, b, 0);
            final_fused_kernel<<<dim3(4, Hh, 1), 256, 0, stream>>>(
                featmap_in, actv, w_c0, b_c0, w_g, b_g, w_b, b_b, mu, rsig, out, b, 0);
        }
    }
}

// Round 2
// 9385.341 us; speedup vs baseline: 3.1092x; 3.1092x over previous
//
#include <hip/hip_runtime.h>
#include <hip/hip_bf16.h>
#include <cstdint>

#define Bn 8
#define Hh 256
#define Ww 256
#define HW 65536
#define SDIM 64
#define LABELS 35
#define NHID 128
#define CHUNK 4                    // input channels per stage == waves per block
#define TR 258                     // f32 tile row stride (floats): [x0][x1..x256][x257]
#define TRB 260                    // bf16 tile row stride (elems): [pad][x0][x1..x256][x257][pad]
#define FSTRIDE (CHUNK * 3 * TR)   // floats per f32 buffer
#define BSTRIDE (CHUNK * 3 * TRB)  // elems per bf16 buffer

static_assert(CHUNK == 4, "stage functions assume 4 waves == CHUNK planes");

static inline __device__ float b2f(__hip_bfloat16 x) { return __bfloat162float(x); }

// ---- async global->LDS dword copy (dest = wave-uniform base + lane*4) ----
__device__ __forceinline__ void gll4(const void* g, void* l) {
    __builtin_amdgcn_global_load_lds(
        (__attribute__((address_space(1))) const void*)(uintptr_t)g,
        (__attribute__((address_space(3))) void*)(uint32_t)(uintptr_t)l, 4, 0, 0);
}

// ---- f32 staging: wave wv stages plane wv, 3 rows, cols gw in [0,256) -> idx [1,257)
__device__ __forceinline__ void stage_f32(float* buf, const float* src,
                                          const float* zrow, int h, int t) {
    const int wv = t >> 6, lane = t & 63;
#pragma unroll
    for (int r = 0; r < 3; r++) {
        int gh = h + r - 1;
        const float* rp = ((unsigned)gh < Hh) ? (src + (size_t)wv * HW + (size_t)gh * Ww) : zrow;
#pragma unroll
        for (int s = 0; s < 4; s++)
            gll4(rp + s * 64 + lane, buf + (wv * 3 + r) * TR + 1 + s * 64);
    }
}

// ---- bf16 staging: wave wv stages plane wv, dwords d = s*64+lane (2 bf16 each)
__device__ __forceinline__ void stage_b16(__hip_bfloat16* buf, const __hip_bfloat16* src,
                                          const __hip_bfloat16* zrow, int h, int t) {
    const int wv = t >> 6, lane = t & 63;
#pragma unroll
    for (int r = 0; r < 3; r++) {
        int gh = h + r - 1;
        const __hip_bfloat16* rp = ((unsigned)gh < Hh) ? (src + (size_t)wv * HW + (size_t)gh * Ww) : zrow;
#pragma unroll
        for (int s = 0; s < 2; s++)
            gll4(rp + (s * 64 + lane) * 2, buf + (wv * 3 + r) * TRB + 2 + s * 128);
    }
}

// ---- compute one CHUNK of input channels (f32 tile) -------------------------
template <int NACC>
__device__ __forceinline__ void conv_chunk_f32(const float* buf, int t,
        const float* const (&wb)[NACC], int icc, int ictot, float (&acc)[NACC][16]) {
#pragma unroll
    for (int ic = 0; ic < CHUNK; ic++) {
        float v[9];
#pragma unroll
        for (int ky = 0; ky < 3; ky++)
#pragma unroll
            for (int kx = 0; kx < 3; kx++)
                v[ky * 3 + kx] = buf[(ic * 3 + ky) * TR + t + kx];
#pragma unroll
        for (int a = 0; a < NACC; a++) {
            const float* wp = wb[a] + (size_t)(icc + ic) * 9;
#pragma unroll
            for (int oc = 0; oc < 16; oc++) {
#pragma unroll
                for (int k = 0; k < 9; k++)
                    acc[a][oc] = fmaf(v[k], wp[(size_t)oc * ictot * 9 + k], acc[a][oc]);
            }
        }
    }
}

// ---- compute one CHUNK of input channels (bf16 tile) ------------------------
template <int NACC>
__device__ __forceinline__ void conv_chunk_b16(const __hip_bfloat16* buf, int t,
        const float* const (&wb)[NACC], int icc, int ictot, float (&acc)[NACC][16]) {
#pragma unroll
    for (int ic = 0; ic < CHUNK; ic++) {
        float v[9];
#pragma unroll
        for (int ky = 0; ky < 3; ky++)
#pragma unroll
            for (int kx = 0; kx < 3; kx++)
                v[ky * 3 + kx] = b2f(buf[(ic * 3 + ky) * TRB + 1 + t + kx]);
#pragma unroll
        for (int a = 0; a < NACC; a++) {
            const float* wp = wb[a] + (size_t)(icc + ic) * 9;
#pragma unroll
            for (int oc = 0; oc < 16; oc++) {
#pragma unroll
                for (int k = 0; k < 9; k++)
                    acc[a][oc] = fmaf(v[k], wp[(size_t)oc * ictot * 9 + k], acc[a][oc]);
            }
        }
    }
}

// ---------------- weight prep: f32 [O][I][9] -> f32 [O][ICP][9], ic zero-pad
__global__ void prep_w(const float* __restrict__ src, float* __restrict__ dst,
                       int OC, int IC, int ICP) {
    int n = OC * ICP * 9;
    for (int idx = blockIdx.x * blockDim.x + threadIdx.x; idx < n; idx += gridDim.x * blockDim.x) {
        int oc = idx / (ICP * 9);
        int r  = idx % (ICP * 9);
        int ic = r / 9;
        int k  = r % 9;
        float v = 0.f;
        if (ic < IC) v = src[(oc * IC + ic) * 9 + k];
        dst[idx] = v;
    }
}

// ---------------- fused: conv1(64->64,lrelu)+masked pooling AND conv_c0 stats
__global__ __launch_bounds__(256) void conv1c0_kernel(
    const float* __restrict__ in,
    const float* __restrict__ w1, const float* __restrict__ b1,
    const float* __restrict__ w0, const float* __restrict__ b0,
    const int* __restrict__ seg, const float* __restrict__ bg,
    const float* __restrict__ mask, const float* __restrict__ zrow,
    float* __restrict__ sums, int* __restrict__ cnts, float* __restrict__ statacc)
{
    __shared__ float tile[2][FSTRIDE];
    __shared__ float s35[LABELS * 16];
    __shared__ int   c35[LABELS];
    __shared__ float wsum[4][16][2];

    const int t = threadIdx.x, h = blockIdx.y, b = blockIdx.z, ocb = blockIdx.x * 16;
    for (int i = t; i < LABELS * 16; i += 256) s35[i] = 0.f;
    if (t < LABELS) c35[t] = 0;
    if (t < 24) { int bu = t / 12, row = t % 12; tile[bu][row * TR] = 0.f; tile[bu][row * TR + 257] = 0.f; }

    float acc[2][16];
#pragma unroll
    for (int i = 0; i < 16; i++) { acc[0][i] = b1[ocb + i]; acc[1][i] = b0[ocb + i]; }

    const float* inb = in + (size_t)b * 64 * HW;
    const float* wb[2] = { w1 + (size_t)ocb * 64 * 9, w0 + (size_t)ocb * 64 * 9 };

    stage_f32(tile[0], inb, zrow, h, t);
    __syncthreads();
    int nb = 0;
    for (int icc = 0; icc < 64; icc += CHUNK) {
        if (icc + CHUNK < 64) stage_f32(tile[nb ^ 1], inb + (size_t)(icc + CHUNK) * HW, zrow, h, t);
        conv_chunk_f32<2>(tile[nb], t, wb, icc, 64, acc);
        __syncthreads();
        nb ^= 1;
    }

    // --- conv1 branch: lrelu + masked class pooling
    int p = h * Ww + t;
    int lab = seg[(size_t)b * HW + p];
    bool m = (bg[(size_t)b * HW + p] != 0.f) && (mask[(size_t)b * HW + p] == 0.f);
    if (m) {
#pragma unroll
        for (int oc = 0; oc < 16; oc++) {
            float o = acc[0][oc];
            o = (o >= 0.f) ? o : 0.2f * o;
            atomicAdd(&s35[lab * 16 + oc], o);
        }
        if (blockIdx.x == 0) atomicAdd(&c35[lab], 1);
    }
    // --- conv_c0 branch: per-channel sum / sumsq
    int lane = t & 63, wv = t >> 6;
#pragma unroll
    for (int oc = 0; oc < 16; oc++) {
        float s = acc[1][oc], ss = acc[1][oc] * acc[1][oc];
#pragma unroll
        for (int off = 32; off > 0; off >>= 1) { s += __shfl_down(s, off); ss += __shfl_down(ss, off); }
        if (lane == 0) { wsum[wv][oc][0] = s; wsum[wv][oc][1] = ss; }
    }
    __syncthreads();
    for (int i = t; i < LABELS * 16; i += 256) {
        float v = s35[i];
        if (v != 0.f) {
            int s = i >> 4, oc = i & 15;
            atomicAdd(&sums[((size_t)b * LABELS + s) * SDIM + ocb + oc], v);
        }
    }
    if (blockIdx.x == 0 && t < LABELS && c35[t] > 0) atomicAdd(&cnts[b * LABELS + t], c35[t]);
    if (t < 16) {
        float S = 0.f, SS = 0.f;
#pragma unroll
        for (int w2 = 0; w2 < 4; w2++) { S += wsum[w2][t][0]; SS += wsum[w2][t][1]; }
        atomicAdd(&statacc[(size_t)(b * SDIM + ocb + t) * 2 + 0], S);
        atomicAdd(&statacc[(size_t)(b * SDIM + ocb + t) * 2 + 1], SS);
    }
}

// ---------------- codes = keep * where(cnt>0, sums/cnt, 0) ------------------
__global__ void codes_kernel(const float* __restrict__ sums, const int* __restrict__ cnts,
                             float* __restrict__ codes) {
    int idx = blockIdx.x * blockDim.x + threadIdx.x;
    if (idx >= Bn * LABELS * SDIM) return;
    int s  = (idx >> 6) % LABELS;
    int bs = idx >> 6;
    int cnt = cnts[bs];
    bool keep = !(s >= 24 && s <= 33);
    codes[idx] = (cnt > 0 && keep) ? sums[idx] / (float)cnt : 0.f;
}

__global__ void finalize_stats(const float* __restrict__ statacc,
                               float* __restrict__ mu, float* __restrict__ rsig) {
    int i = blockIdx.x * blockDim.x + threadIdx.x;
    if (i >= Bn * SDIM) return;
    float S = statacc[2 * i], SS = statacc[2 * i + 1];
    float m = S / (float)HW;
    float v = SS / (float)HW - m * m;
    mu[i] = m;
    rsig[i] = rsqrtf(v + 1e-5f);
}

// ---------------- conv_sh with out_map generated on the fly -----------------
// channels: 0..63 style (codes[lab][f]*bg), 64..98 one-hot*bg, 99 zero (pad)
__global__ __launch_bounds__(256) void conv_sh_kernel(
    const int* __restrict__ seg, const float* __restrict__ bg,
    const float* __restrict__ codes, const float* __restrict__ wf,
    const float* __restrict__ bf, __hip_bfloat16* __restrict__ actv,
    int b0, int abstride)
{
    __shared__ float tile[2][FSTRIDE];
    __shared__ float cod[LABELS * 65];   // stride 65: conflict-free lab lookup

    const int t = threadIdx.x, h = blockIdx.y, ocb = blockIdx.x * 16;
    const int b = b0 + blockIdx.z;
    const int*   seg_b   = seg + (size_t)b * HW;
    const float* bg_b    = bg + (size_t)b * HW;
    const float* codes_b = codes + (size_t)b * LABELS * SDIM;
    __hip_bfloat16* actv_b = actv + (size_t)blockIdx.z * abstride;

    for (int i = t; i < LABELS * SDIM; i += 256) cod[(i >> 6) * 65 + (i & 63)] = codes_b[i];
    if (t < 24) { int bu = t / 12, row = t % 12; tile[bu][row * TR] = 0.f; tile[bu][row * TR + 257] = 0.f; }

    // per-thread lab/bg for 3 rows at gw = t (thread t stages column x = t+1)
    int lab3[3]; float bg3[3];
#pragma unroll
    for (int r = 0; r < 3; r++) {
        int gh = h + r - 1;
        if ((unsigned)gh < Hh) { lab3[r] = seg_b[gh * Ww + t]; bg3[r] = bg_b[gh * Ww + t]; }
        else                   { lab3[r] = 0; bg3[r] = 0.f; }
    }

    float acc[1][16];
#pragma unroll
    for (int i = 0; i < 16; i++) acc[0][i] = bf[ocb + i];
    const float* wb[1] = { wf + (size_t)ocb * 100 * 9 };

    auto stage_sh = [&](float* buf, int icc) {
#pragma unroll
        for (int ic = 0; ic < CHUNK; ic++) {
            int gic = icc + ic;
#pragma unroll
            for (int r = 0; r < 3; r++) {
                float bgv = bg3[r]; int lab = lab3[r];
                float v;
                if (gic < 64)      v = cod[lab * 65 + gic] * bgv;
                else if (gic < 99) v = ((gic - 64) == lab) ? bgv : 0.f;
                else               v = 0.f;
                buf[(ic * 3 + r) * TR + t + 1] = v;
            }
        }
    };

    __syncthreads();             // cod + zero slots visible
    stage_sh(tile[0], 0);
    __syncthreads();
    int nb = 0;
    for (int icc = 0; icc < 100; icc += CHUNK) {
        if (icc + CHUNK < 100) stage_sh(tile[nb ^ 1], icc + CHUNK);
        conv_chunk_f32<1>(tile[nb], t, wb, icc, 100, acc);
        __syncthreads();
        nb ^= 1;
    }

#pragma unroll
    for (int oc = 0; oc < 16; oc++) {
        float o = fmaxf(acc[0][oc], 0.f);   // relu
        actv_b[(size_t)(ocb + oc) * HW + h * Ww + t] = __float2bfloat16(o);
    }
}

// ---------------- fused: dx=conv_c0, gamma/beta convs, IN + lrelu -----------
__global__ __launch_bounds__(256) void final_fused_kernel(
    const float* __restrict__ fin, const __hip_bfloat16* __restrict__ actv,
    const float* __restrict__ wc0, const float* __restrict__ bc0,
    const float* __restrict__ wg,  const float* __restrict__ bg2,
    const float* __restrict__ wb2, const float* __restrict__ bb2,
    const float* __restrict__ mu, const float* __restrict__ rsig,
    const float* __restrict__ zrow, float* __restrict__ out, int b0, int abstride)
{
    __shared__ float tile[2][FSTRIDE];
    const int t = threadIdx.x, h = blockIdx.y, ocb = blockIdx.x * 16;
    const int b = b0 + blockIdx.z;
    const float* fin_b = fin + (size_t)b * 64 * HW;
    const __hip_bfloat16* actv_b = actv + (size_t)blockIdx.z * abstride;

    if (t < 24) { int bu = t / 12, row = t % 12; tile[bu][row * TR] = 0.f; tile[bu][row * TR + 257] = 0.f; }

    // ---- pass 1: dx = conv_c0(featmap_in), f32 tile
    float accd[1][16];
#pragma unroll
    for (int i = 0; i < 16; i++) accd[0][i] = bc0[ocb + i];
    const float* wbd[1] = { wc0 + (size_t)ocb * 64 * 9 };

    stage_f32(tile[0], fin_b, zrow, h, t);
    __syncthreads();
    int nb = 0;
    for (int icc = 0; icc < 64; icc += CHUNK) {
        if (icc + CHUNK < 64) stage_f32(tile[nb ^ 1], fin_b + (size_t)(icc + CHUNK) * HW, zrow, h, t);
        conv_chunk_f32<1>(tile[nb], t, wbd, icc, 64, accd);
        __syncthreads();
        nb ^= 1;
    }

    // ---- pass 2: gamma/beta convs over actv, bf16 tile (aliases f32 tile)
    __hip_bfloat16* tb = (__hip_bfloat16*)&tile[0][0];
    if (t < 24) {   // permanent zeros: e=1 (x=0) and e=258 (x=257) per row, both bufs
        int bu = t / 12, row = t % 12;
        tb[bu * BSTRIDE + row * TRB + 1]   = __float2bfloat16(0.f);
        tb[bu * BSTRIDE + row * TRB + 258] = __float2bfloat16(0.f);
    }
    float accgb[2][16];
#pragma unroll
    for (int i = 0; i < 16; i++) { accgb[0][i] = bg2[ocb + i]; accgb[1][i] = bb2[ocb + i]; }
    const float* wbgb[2] = { wg + (size_t)ocb * 128 * 9, wb2 + (size_t)ocb * 128 * 9 };
    const __hip_bfloat16* zb = (const __hip_bfloat16*)zrow;

    stage_b16(tb, actv_b, zb, h, t);
    __syncthreads();
    nb = 0;
    for (int icc = 0; icc < 128; icc += CHUNK) {
        if (icc + CHUNK < 128)
            stage_b16(tb + (nb ^ 1) * BSTRIDE, actv_b + (size_t)(icc + CHUNK) * HW, zb, h, t);
        conv_chunk_b16<2>(tb + nb * BSTRIDE, t, wbgb, icc, 128, accgb);
        __syncthreads();
        nb ^= 1;
    }

    const float* mu_b = mu + b * SDIM;
    const float* rs_b = rsig + b * SDIM;
    float* out_b = out + (size_t)b * SDIM * HW;
#pragma unroll
    for (int oc = 0; oc < 16; oc++) {
        int c = ocb + oc;
        float nrm = (accd[0][oc] - mu_b[c]) * rs_b[c];
        float o = nrm * (1.f + accgb[0][oc]) + accgb[1][oc];
        o = (o >= 0.f) ? o : 0.2f * o;
        out_b[(size_t)c * HW + h * Ww + t] = o;
    }
}

// ===========================================================================
extern "C" void kernel_launch(void* const* d_in, const int* in_sizes, int n_in,
                              void* d_out, int out_size, void* d_ws, size_t ws_size,
                              hipStream_t stream) {
    const float* featmap_in = (const float*)d_in[0];
    const int*   seg        = (const int*)d_in[1];
    const float* bg         = (const float*)d_in[2];
    const float* mask       = (const float*)d_in[3];
    const float* w_conv     = (const float*)d_in[4];
    const float* b_conv     = (const float*)d_in[5];
    const float* w_c0       = (const float*)d_in[6];
    const float* b_c0       = (const float*)d_in[7];
    const float* w_sh       = (const float*)d_in[8];
    const float* b_sh       = (const float*)d_in[9];
    const float* w_g        = (const float*)d_in[10];
    const float* b_g        = (const float*)d_in[11];
    const float* w_b        = (const float*)d_in[12];
    const float* b_b        = (const float*)d_in[13];
    float* out = (float*)d_out;

    // ---- workspace arena ----
    char* ws = (char*)d_ws;
    size_t o = 0;
    auto alloc = [&](size_t bytes) -> char* {
        size_t r = o; o = (o + bytes + 255) & ~(size_t)255; return ws + r;
    };
    float* wf_sh   = (float*)alloc((size_t)128 * 100 * 9 * 4);
    float* sums    = (float*)alloc((size_t)Bn * LABELS * SDIM * 4);
    int*   cnts    = (int*)alloc((size_t)Bn * LABELS * 4);
    float* codes   = (float*)alloc((size_t)Bn * LABELS * SDIM * 4);
    float* statacc = (float*)alloc((size_t)Bn * SDIM * 2 * 4);
    float* mu      = (float*)alloc((size_t)Bn * SDIM * 4);
    float* rsig    = (float*)alloc((size_t)Bn * SDIM * 4);
    float* zrow    = (float*)alloc(256 * 4);             // 1 KB zero row (OOB source)
    size_t actv_full = (size_t)Bn * NHID * HW * 2;       // 134 MB (bf16, all batches)
    size_t actv_one  = (size_t)NHID * HW * 2;            // 16.8 MB
    bool batched = (ws_size > o) && ((ws_size - o) >= actv_full + 512);
    __hip_bfloat16* actv = (__hip_bfloat16*)alloc(batched ? actv_full : actv_one);

    prep_w<<<450, 256, 0, stream>>>(w_sh, wf_sh, 128, 99, 100);

    hipMemsetAsync(sums, 0, (size_t)Bn * LABELS * SDIM * 4, stream);
    hipMemsetAsync(cnts, 0, (size_t)Bn * LABELS * 4, stream);
    hipMemsetAsync(statacc, 0, (size_t)Bn * SDIM * 2 * 4, stream);
    hipMemsetAsync(zrow, 0, 256 * 4, stream);

    conv1c0_kernel<<<dim3(4, Hh, Bn), 256, 0, stream>>>(
        featmap_in, w_conv, b_conv, w_c0, b_c0, seg, bg, mask, zrow, sums, cnts, statacc);
    codes_kernel<<<(Bn * LABELS * SDIM + 255) / 256, 256, 0, stream>>>(sums, cnts, codes);
    finalize_stats<<<2, 256, 0, stream>>>(statacc, mu, rsig);

    if (batched) {
        conv_sh_kernel<<<dim3(8, Hh, Bn), 256, 0, stream>>>(
            seg, bg, codes, wf_sh, b_sh, actv, 0, NHID * HW);
        final_fused_kernel<<<dim3(4, Hh, Bn), 256, 0, stream>>>(
            featmap_in, actv, w_c0, b_c0, w_g, b_g, w_b, b_b, mu, rsig, zrow, out, 0, NHID * HW);
    } else {
        for (int b = 0; b < Bn; b++) {
            conv_sh_kernel<<<dim3(8, Hh, 1), 256, 0, stream>>>(
                seg, bg, codes, wf_sh, b_sh, actv, b, 0);
            final_fused_kernel<<<dim3(4, Hh, 1), 256, 0, stream>>>(
                featmap_in, actv, w_c0, b_c0, w_g, b_g, w_b, b_b, mu, rsig, zrow, out, b, 0);
        }
    }
}

// Round 4
// 5925.857 us; speedup vs baseline: 4.9243x; 1.5838x over previous
//
#include <hip/hip_runtime.h>
#include <hip/hip_bf16.h>
#include <cstdint>

#define Bn 8
#define Hh 256
#define Ww 256
#define HW 65536
#define SDIM 64
#define LABELS 35
#define NHID 128
#define CHUNK 4                    // input channels per stage == waves per block
#define TR 264                     // f32 tile row stride (floats); interior at +4 (16B-aligned)
#define FSTRIDE (CHUNK * 3 * TR)   // floats per f32 buffer (3168)

typedef __attribute__((ext_vector_type(8))) short bf16x8;   // 8 bf16 = 4 VGPR (MFMA A/B frag)
typedef __attribute__((ext_vector_type(4))) float f32x4;    // MFMA C/D frag

// ---- async global->LDS 16B copy: dest = wave-uniform base + lane*16, src per-lane
__device__ __forceinline__ void gll16(const void* g, void* l) {
    __builtin_amdgcn_global_load_lds(
        (__attribute__((address_space(1))) const void*)(uintptr_t)g,
        (__attribute__((address_space(3))) void*)(uint32_t)(uintptr_t)l, 16, 0, 0);
}

// ---- f32 staging: wave wv stages plane wv, 3 rows; one gll16 covers 256 floats
__device__ __forceinline__ void stage_f32(float* buf, const float* src,
                                          const float* zrow, int h, int t) {
    const int wv = t >> 6, lane = t & 63;
#pragma unroll
    for (int r = 0; r < 3; r++) {
        int gh = h + r - 1;
        const float* rp = ((unsigned)gh < Hh) ? (src + (size_t)wv * HW + (size_t)gh * Ww) : zrow;
        gll16(rp + lane * 4, buf + (wv * 3 + r) * TR + 4);
    }
}

// ---- compute one CHUNK of input channels (f32 tile, interior at slot gw+4) ----
template <int NACC>
__device__ __forceinline__ void conv_chunk_f32(const float* buf, int t,
        const float* const (&wb)[NACC], int icc, int ictot, float (&acc)[NACC][16]) {
#pragma unroll
    for (int ic = 0; ic < CHUNK; ic++) {
        float v[9];
#pragma unroll
        for (int ky = 0; ky < 3; ky++)
#pragma unroll
            for (int kx = 0; kx < 3; kx++)
                v[ky * 3 + kx] = buf[(ic * 3 + ky) * TR + t + 3 + kx];
#pragma unroll
        for (int a = 0; a < NACC; a++) {
            const float* wp = wb[a] + (size_t)(icc + ic) * 9;
#pragma unroll
            for (int oc = 0; oc < 16; oc++) {
#pragma unroll
                for (int k = 0; k < 9; k++)
                    acc[a][oc] = fmaf(v[k], wp[(size_t)oc * ictot * 9 + k], acc[a][oc]);
            }
        }
    }
}

// ---------------- weight prep: f32 [O][I][9] -> f32 [O][ICP][9], ic zero-pad
__global__ void prep_w(const float* __restrict__ src, float* __restrict__ dst,
                       int OC, int IC, int ICP) {
    int n = OC * ICP * 9;
    for (int idx = blockIdx.x * blockDim.x + threadIdx.x; idx < n; idx += gridDim.x * blockDim.x) {
        int oc = idx / (ICP * 9);
        int r  = idx % (ICP * 9);
        int ic = r / 9;
        int k  = r % 9;
        float v = 0.f;
        if (ic < IC) v = src[(oc * IC + ic) * 9 + k];
        dst[idx] = v;
    }
}

// ---------------- MFMA A-fragment prep for gamma/beta weights --------------
// layout: [(mat*2+hl)*4 + ocb][kstep=icq*9+tap][oc16][k32] bf16; hi/lo split of fp32
__global__ void prep_wfrag(const float* __restrict__ wg, const float* __restrict__ wb2,
                           ushort* __restrict__ dst) {
    const int N = 16 * 36 * 512;   // 294912
    for (int idx = blockIdx.x * blockDim.x + threadIdx.x; idx < N; idx += gridDim.x * blockDim.x) {
        int k = idx & 31, oc = (idx >> 5) & 15;
        int blk = idx >> 9;
        int ks = blk % 36, q = blk / 36;
        int ocbI = q & 3, q4 = q >> 2, hl = q4 & 1, mat = q4 >> 1;
        int icq = ks / 9, tap = ks % 9;
        int OC = ocbI * 16 + oc, ic = icq * 32 + k;
        const float* w = mat ? wb2 : wg;
        float v = w[((size_t)OC * 128 + ic) * 9 + tap];
        __hip_bfloat16 h16 = __float2bfloat16(v);
        if (hl) { float r = v - __bfloat162float(h16); h16 = __float2bfloat16(r); }
        dst[idx] = *(ushort*)&h16;
    }
}

// ---------------- fused: conv1(64->64,lrelu)+masked pooling AND conv_c0 stats
__global__ __launch_bounds__(256) void conv1c0_kernel(
    const float* __restrict__ in,
    const float* __restrict__ w1, const float* __restrict__ b1,
    const float* __restrict__ w0, const float* __restrict__ b0,
    const int* __restrict__ seg, const float* __restrict__ bg,
    const float* __restrict__ mask, const float* __restrict__ zrow,
    float* __restrict__ sums, int* __restrict__ cnts, float* __restrict__ statacc)
{
    __shared__ __align__(16) float tile[2][FSTRIDE];
    __shared__ float s35[LABELS * 16];
    __shared__ int   c35[LABELS];
    __shared__ float wsum[4][16][2];

    const int t = threadIdx.x, h = blockIdx.y, b = blockIdx.z, ocb = blockIdx.x * 16;
    for (int i = t; i < LABELS * 16; i += 256) s35[i] = 0.f;
    if (t < LABELS) c35[t] = 0;
    if (t < 48) { int bu = t / 24, rr = (t % 24) >> 1, sl = (t & 1) ? TR - 4 : 3;
                  tile[bu][rr * TR + sl] = 0.f; }

    float acc[2][16];
#pragma unroll
    for (int i = 0; i < 16; i++) { acc[0][i] = b1[ocb + i]; acc[1][i] = b0[ocb + i]; }

    const float* inb = in + (size_t)b * 64 * HW;
    const float* wb[2] = { w1 + (size_t)ocb * 64 * 9, w0 + (size_t)ocb * 64 * 9 };

    stage_f32(tile[0], inb, zrow, h, t);
    __syncthreads();
    int nb = 0;
    for (int icc = 0; icc < 64; icc += CHUNK) {
        if (icc + CHUNK < 64) stage_f32(tile[nb ^ 1], inb + (size_t)(icc + CHUNK) * HW, zrow, h, t);
        conv_chunk_f32<2>(tile[nb], t, wb, icc, 64, acc);
        __syncthreads();
        nb ^= 1;
    }

    // --- conv1 branch: lrelu + masked class pooling
    int p = h * Ww + t;
    int lab = seg[(size_t)b * HW + p];
    bool m = (bg[(size_t)b * HW + p] != 0.f) && (mask[(size_t)b * HW + p] == 0.f);
    if (m) {
#pragma unroll
        for (int oc = 0; oc < 16; oc++) {
            float o = acc[0][oc];
            o = (o >= 0.f) ? o : 0.2f * o;
            atomicAdd(&s35[lab * 16 + oc], o);
        }
        if (blockIdx.x == 0) atomicAdd(&c35[lab], 1);
    }
    // --- conv_c0 branch: per-channel sum / sumsq
    int lane = t & 63, wv = t >> 6;
#pragma unroll
    for (int oc = 0; oc < 16; oc++) {
        float s = acc[1][oc], ss = acc[1][oc] * acc[1][oc];
#pragma unroll
        for (int off = 32; off > 0; off >>= 1) { s += __shfl_down(s, off); ss += __shfl_down(ss, off); }
        if (lane == 0) { wsum[wv][oc][0] = s; wsum[wv][oc][1] = ss; }
    }
    __syncthreads();
    for (int i = t; i < LABELS * 16; i += 256) {
        float v = s35[i];
        if (v != 0.f) {
            int s = i >> 4, oc = i & 15;
            atomicAdd(&sums[((size_t)b * LABELS + s) * SDIM + ocb + oc], v);
        }
    }
    if (blockIdx.x == 0 && t < LABELS && c35[t] > 0) atomicAdd(&cnts[b * LABELS + t], c35[t]);
    if (t < 16) {
        float S = 0.f, SS = 0.f;
#pragma unroll
        for (int w2 = 0; w2 < 4; w2++) { S += wsum[w2][t][0]; SS += wsum[w2][t][1]; }
        atomicAdd(&statacc[(size_t)(b * SDIM + ocb + t) * 2 + 0], S);
        atomicAdd(&statacc[(size_t)(b * SDIM + ocb + t) * 2 + 1], SS);
    }
}

// ---------------- codes = keep * where(cnt>0, sums/cnt, 0) ------------------
__global__ void codes_kernel(const float* __restrict__ sums, const int* __restrict__ cnts,
                             float* __restrict__ codes) {
    int idx = blockIdx.x * blockDim.x + threadIdx.x;
    if (idx >= Bn * LABELS * SDIM) return;
    int s  = (idx >> 6) % LABELS;
    int bs = idx >> 6;
    int cnt = cnts[bs];
    bool keep = !(s >= 24 && s <= 33);
    codes[idx] = (cnt > 0 && keep) ? sums[idx] / (float)cnt : 0.f;
}

__global__ void finalize_stats(const float* __restrict__ statacc,
                               float* __restrict__ mu, float* __restrict__ rsig) {
    int i = blockIdx.x * blockDim.x + threadIdx.x;
    if (i >= Bn * SDIM) return;
    float S = statacc[2 * i], SS = statacc[2 * i + 1];
    float m = S / (float)HW;
    float v = SS / (float)HW - m * m;
    mu[i] = m;
    rsig[i] = rsqrtf(v + 1e-5f);
}

// ---------------- conv_sh; actv written CHANNEL-LAST [h][x][ic128] bf16 -----
// with XOR ic-group swizzle baked into global layout: phys16Bunit = logical ^ s(x)
__global__ __launch_bounds__(256) void conv_sh_kernel(
    const int* __restrict__ seg, const float* __restrict__ bg,
    const float* __restrict__ codes, const float* __restrict__ wf,
    const float* __restrict__ bf, __hip_bfloat16* __restrict__ actv,
    int b0, int abstride)
{
    __shared__ __align__(16) float tile[2][FSTRIDE];
    __shared__ float cod[LABELS * 65];   // stride 65: conflict-free lab lookup

    const int t = threadIdx.x, h = blockIdx.y, bxI = blockIdx.x, ocb = bxI * 16;
    const int b = b0 + blockIdx.z;
    const int*   seg_b   = seg + (size_t)b * HW;
    const float* bg_b    = bg + (size_t)b * HW;
    const float* codes_b = codes + (size_t)b * LABELS * SDIM;
    __hip_bfloat16* actv_b = actv + (size_t)blockIdx.z * abstride;

    for (int i = t; i < LABELS * SDIM; i += 256) cod[(i >> 6) * 65 + (i & 63)] = codes_b[i];
    if (t < 48) { int bu = t / 24, rr = (t % 24) >> 1, sl = (t & 1) ? TR - 4 : 3;
                  tile[bu][rr * TR + sl] = 0.f; }

    // per-thread lab/bg for 3 rows at gw = t
    int lab3[3]; float bg3[3];
#pragma unroll
    for (int r = 0; r < 3; r++) {
        int gh = h + r - 1;
        if ((unsigned)gh < Hh) { lab3[r] = seg_b[gh * Ww + t]; bg3[r] = bg_b[gh * Ww + t]; }
        else                   { lab3[r] = 0; bg3[r] = 0.f; }
    }

    float acc[1][16];
#pragma unroll
    for (int i = 0; i < 16; i++) acc[0][i] = bf[ocb + i];
    const float* wb[1] = { wf + (size_t)ocb * 100 * 9 };

    auto stage_sh = [&](float* buf, int icc) {
#pragma unroll
        for (int ic = 0; ic < CHUNK; ic++) {
            int gic = icc + ic;
#pragma unroll
            for (int r = 0; r < 3; r++) {
                float bgv = bg3[r]; int lab = lab3[r];
                float v;
                if (gic < 64)      v = cod[lab * 65 + gic] * bgv;
                else if (gic < 99) v = ((gic - 64) == lab) ? bgv : 0.f;
                else               v = 0.f;
                buf[(ic * 3 + r) * TR + t + 4] = v;
            }
        }
    };

    __syncthreads();             // cod + zero slots visible
    stage_sh(tile[0], 0);
    __syncthreads();
    int nb = 0;
    for (int icc = 0; icc < 100; icc += CHUNK) {
        if (icc + CHUNK < 100) stage_sh(tile[nb ^ 1], icc + CHUNK);
        conv_chunk_f32<1>(tile[nb], t, wb, icc, 100, acc);
        __syncthreads();
        nb ^= 1;
    }

    // relu + pack 16 oc -> two swizzled 16B units of channel-last cell (h, x=t)
    int x = t;
    int s = (x ^ (x >> 2)) & 3;
    int quarter = bxI >> 1;            // ic-quarter (32-ch group) these oc land in
    int m0 = (bxI & 1) * 2;            // logical 16B-unit index within quarter
    uint pk[8];
#pragma unroll
    for (int i = 0; i < 8; i++) {
        float lo = fmaxf(acc[0][2 * i], 0.f), hi = fmaxf(acc[0][2 * i + 1], 0.f);
        __hip_bfloat16 l16 = __float2bfloat16(lo), h16 = __float2bfloat16(hi);
        pk[i] = (uint)*(ushort*)&l16 | ((uint)*(ushort*)&h16 << 16);
    }
    char* cell = (char*)actv_b + (((size_t)h * 256 + x) << 8) + (quarter << 6);
    *(uint4*)(cell + (((m0 + 0) ^ s) << 4)) = make_uint4(pk[0], pk[1], pk[2], pk[3]);
    *(uint4*)(cell + (((m0 + 1) ^ s) << 4)) = make_uint4(pk[4], pk[5], pk[6], pk[7]);
}

// ---------------- fused: dx=conv_c0 (VALU) + gamma/beta convs (MFMA) + IN + lrelu
__global__ __launch_bounds__(256) void final_fused_kernel(
    const float* __restrict__ fin, const __hip_bfloat16* __restrict__ actv,
    const float* __restrict__ wc0, const float* __restrict__ bc0,
    const ushort* __restrict__ wfrag,
    const float* __restrict__ bg2, const float* __restrict__ bb2,
    const float* __restrict__ mu, const float* __restrict__ rsig,
    const float* __restrict__ zrow, float* __restrict__ out, int b0, int abstride)
{
    __shared__ __align__(16) char smem[49536];
    const int t = threadIdx.x, h = blockIdx.y, bxI = blockIdx.x, ocb = bxI * 16;
    const int b = b0 + blockIdx.z;
    const int l = t & 63, wv = t >> 6;
    const float* fin_b = fin + (size_t)b * 64 * HW;
    const char* actv_b = (const char*)(actv + (size_t)blockIdx.z * abstride);

    // ---- pass 1: dx = conv_c0(featmap_in), fp32 VALU, double-buffered ----
    float* tf = (float*)smem;
    if (t < 48) { int bu = t / 24, rr = (t % 24) >> 1, sl = (t & 1) ? TR - 4 : 3;
                  tf[bu * FSTRIDE + rr * TR + sl] = 0.f; }
    float accd[1][16];
#pragma unroll
    for (int i = 0; i < 16; i++) accd[0][i] = bc0[ocb + i];
    const float* wbd[1] = { wc0 + (size_t)ocb * 64 * 9 };

    stage_f32(tf, fin_b, zrow, h, t);
    __syncthreads();
    int nb = 0;
    for (int icc = 0; icc < 64; icc += CHUNK) {
        if (icc + CHUNK < 64) stage_f32(tf + (nb ^ 1) * FSTRIDE, fin_b + (size_t)(icc + CHUNK) * HW, zrow, h, t);
        conv_chunk_f32<1>(tf + nb * FSTRIDE, t, wbd, icc, 64, accd);
        __syncthreads();
        nb ^= 1;
    }

    // ---- pass 2: gamma/beta via MFMA over channel-last bf16 actv ----
    // LDS tile: [3 rows][258 x-cells][4 units of 8 ic] bf16x8, single-buffered
    bf16x8* tileB = (bf16x8*)smem;
    if (t < 24) { int rr = t >> 3, half = (t >> 2) & 1, u = t & 3;
        bf16x8 z = {0, 0, 0, 0, 0, 0, 0, 0};
        tileB[(rr * 258 + (half ? 257 : 0)) * 4 + u] = z; }

    f32x4 accg[4], accb[4];
#pragma unroll
    for (int j = 0; j < 4; j++) {
        int c = ocb + ((l >> 4) << 2) + j;
        float vg = bg2[c], vb = bb2[c];
#pragma unroll
        for (int pt = 0; pt < 4; pt++) { accg[pt][j] = vg; accb[pt][j] = vb; }
    }

    const char* wfA = (const char*)wfrag;
    const int loff = ((l & 15) << 6) + ((l >> 4) << 4);   // A-frag lane byte offset

    for (int icq = 0; icq < 4; icq++) {
        // stage 32-ic chunk: 48 gll16 split over 4 waves (linear dest, swizzle in global)
#pragma unroll
        for (int i = 0; i < 12; i++) {
            int k = wv * 12 + i;
            int r = k >> 4;
            int n = ((k & 15) << 6) + l;
            int gh = h + r - 1;
            const char* src = ((unsigned)gh < Hh)
                ? actv_b + (((size_t)gh * 256 + (n >> 2)) << 8) + (icq << 6) + ((n & 3) << 4)
                : (const char*)zrow + (l << 4);
            gll16(src, &tileB[((r * 258 + 1) << 2) + ((k & 15) << 6)]);
        }
        __syncthreads();
#pragma unroll
        for (int tap = 0; tap < 9; tap++) {
            const int ky = tap / 3, kx = tap % 3;
            const int ks = icq * 9 + tap;
            const bf16x8 agh = *(const bf16x8*)(wfA + ((size_t)(((0 * 4 + bxI) * 36 + ks)) << 10) + loff);
            const bf16x8 agl = *(const bf16x8*)(wfA + ((size_t)(((1 * 4 + bxI) * 36 + ks)) << 10) + loff);
            const bf16x8 abh = *(const bf16x8*)(wfA + ((size_t)(((2 * 4 + bxI) * 36 + ks)) << 10) + loff);
            const bf16x8 abl = *(const bf16x8*)(wfA + ((size_t)(((3 * 4 + bxI) * 36 + ks)) << 10) + loff);
#pragma unroll
            for (int pt = 0; pt < 4; pt++) {
                int xs = (wv << 6) + (pt << 4) + (l & 15) + kx;
                int gm = xs - 1;
                int gph = (l >> 4) ^ ((gm ^ (gm >> 2)) & 3);
                bf16x8 bfr = tileB[((ky * 258 + xs) << 2) + gph];
                accg[pt] = __builtin_amdgcn_mfma_f32_16x16x32_bf16(agh, bfr, accg[pt], 0, 0, 0);
                accg[pt] = __builtin_amdgcn_mfma_f32_16x16x32_bf16(agl, bfr, accg[pt], 0, 0, 0);
                accb[pt] = __builtin_amdgcn_mfma_f32_16x16x32_bf16(abh, bfr, accb[pt], 0, 0, 0);
                accb[pt] = __builtin_amdgcn_mfma_f32_16x16x32_bf16(abl, bfr, accb[pt], 0, 0, 0);
            }
        }
        __syncthreads();
    }

    // ---- epilogue: hand dx across lanes via LDS (stride 260 = 2-way free) ----
    float* dxl = (float*)smem;
#pragma unroll
    for (int oc = 0; oc < 16; oc++) dxl[oc * 260 + t] = accd[0][oc];
    __syncthreads();

    const float* mu_b = mu + b * SDIM;
    const float* rs_b = rsig + b * SDIM;
    float* out_b = out + (size_t)b * SDIM * HW;
    float muj[4], rsj[4];
#pragma unroll
    for (int j = 0; j < 4; j++) { int c = ocb + ((l >> 4) << 2) + j; muj[j] = mu_b[c]; rsj[j] = rs_b[c]; }
#pragma unroll
    for (int pt = 0; pt < 4; pt++) {
        int px = (wv << 6) + (pt << 4) + (l & 15);
#pragma unroll
        for (int j = 0; j < 4; j++) {
            int cl = ((l >> 4) << 2) + j;
            float nrm = (dxl[cl * 260 + px] - muj[j]) * rsj[j];
            float o = nrm * (1.f + accg[pt][j]) + accb[pt][j];
            o = (o >= 0.f) ? o : 0.2f * o;
            out_b[(size_t)(ocb + cl) * HW + h * Ww + px] = o;
        }
    }
}

// ===========================================================================
extern "C" void kernel_launch(void* const* d_in, const int* in_sizes, int n_in,
                              void* d_out, int out_size, void* d_ws, size_t ws_size,
                              hipStream_t stream) {
    const float* featmap_in = (const float*)d_in[0];
    const int*   seg        = (const int*)d_in[1];
    const float* bg         = (const float*)d_in[2];
    const float* mask       = (const float*)d_in[3];
    const float* w_conv     = (const float*)d_in[4];
    const float* b_conv     = (const float*)d_in[5];
    const float* w_c0       = (const float*)d_in[6];
    const float* b_c0       = (const float*)d_in[7];
    const float* w_sh       = (const float*)d_in[8];
    const float* b_sh       = (const float*)d_in[9];
    const float* w_g        = (const float*)d_in[10];
    const float* b_g        = (const float*)d_in[11];
    const float* w_b        = (const float*)d_in[12];
    const float* b_b        = (const float*)d_in[13];
    float* out = (float*)d_out;

    // ---- workspace arena ----
    char* ws = (char*)d_ws;
    size_t o = 0;
    auto alloc = [&](size_t bytes) -> char* {
        size_t r = o; o = (o + bytes + 255) & ~(size_t)255; return ws + r;
    };
    float*  wf_sh   = (float*)alloc((size_t)128 * 100 * 9 * 4);
    ushort* wfrag   = (ushort*)alloc((size_t)16 * 36 * 512 * 2);   // 589824 B
    float*  sums    = (float*)alloc((size_t)Bn * LABELS * SDIM * 4);
    int*    cnts    = (int*)alloc((size_t)Bn * LABELS * 4);
    float*  codes   = (float*)alloc((size_t)Bn * LABELS * SDIM * 4);
    float*  statacc = (float*)alloc((size_t)Bn * SDIM * 2 * 4);
    float*  mu      = (float*)alloc((size_t)Bn * SDIM * 4);
    float*  rsig    = (float*)alloc((size_t)Bn * SDIM * 4);
    float*  zrow    = (float*)alloc(256 * 4);            // 1 KB zero row (OOB source)
    size_t actv_full = (size_t)Bn * NHID * HW * 2;       // 134 MB (bf16, all batches)
    size_t actv_one  = (size_t)NHID * HW * 2;            // 16.8 MB
    bool batched = (ws_size > o) && ((ws_size - o) >= actv_full + 512);
    __hip_bfloat16* actv = (__hip_bfloat16*)alloc(batched ? actv_full : actv_one);

    prep_w<<<450, 256, 0, stream>>>(w_sh, wf_sh, 128, 99, 100);
    prep_wfrag<<<288, 256, 0, stream>>>(w_g, w_b, wfrag);

    hipMemsetAsync(sums, 0, (size_t)Bn * LABELS * SDIM * 4, stream);
    hipMemsetAsync(cnts, 0, (size_t)Bn * LABELS * 4, stream);
    hipMemsetAsync(statacc, 0, (size_t)Bn * SDIM * 2 * 4, stream);
    hipMemsetAsync(zrow, 0, 256 * 4, stream);

    conv1c0_kernel<<<dim3(4, Hh, Bn), 256, 0, stream>>>(
        featmap_in, w_conv, b_conv, w_c0, b_c0, seg, bg, mask, zrow, sums, cnts, statacc);
    codes_kernel<<<(Bn * LABELS * SDIM + 255) / 256, 256, 0, stream>>>(sums, cnts, codes);
    finalize_stats<<<2, 256, 0, stream>>>(statacc, mu, rsig);

    if (batched) {
        conv_sh_kernel<<<dim3(8, Hh, Bn), 256, 0, stream>>>(
            seg, bg, codes, wf_sh, b_sh, actv, 0, NHID * HW);
        final_fused_kernel<<<dim3(4, Hh, Bn), 256, 0, stream>>>(
            featmap_in, actv, w_c0, b_c0, wfrag, b_g, b_b, mu, rsig, zrow, out, 0, NHID * HW);
    } else {
        for (int b = 0; b < Bn; b++) {
            conv_sh_kernel<<<dim3(8, Hh, 1), 256, 0, stream>>>(
                seg, bg, codes, wf_sh, b_sh, actv, b, 0);
            final_fused_kernel<<<dim3(4, Hh, 1), 256, 0, stream>>>(
                featmap_in, actv, w_c0, b_c0, wfrag, b_g, b_b, mu, rsig, zrow, out, b, 0);
        }
    }
}

// Round 5
// 3181.536 us; speedup vs baseline: 9.1719x; 1.8626x over previous
//
#include <hip/hip_runtime.h>
#include <hip/hip_bf16.h>
#include <cstdint>

#define Bn 8
#define Hh 256
#define Ww 256
#define HW 65536
#define SDIM 64
#define LABELS 35
#define NHID 128
#define CHUNK 4                    // input channels per stage == waves per block
#define TR 264                     // f32 tile row stride (floats); interior at +4 (16B-aligned)
#define FSTRIDE (CHUNK * 3 * TR)   // floats per f32 buffer (3168)

typedef __attribute__((ext_vector_type(8))) short bf16x8;   // 8 bf16 = 4 VGPR (MFMA A/B frag)
typedef __attribute__((ext_vector_type(4))) float f32x4;    // MFMA C/D frag

// ---- async global->LDS 16B copy: dest = wave-uniform base + lane*16, src per-lane
__device__ __forceinline__ void gll16(const void* g, void* l) {
    __builtin_amdgcn_global_load_lds(
        (__attribute__((address_space(1))) const void*)(uintptr_t)g,
        (__attribute__((address_space(3))) void*)(uint32_t)(uintptr_t)l, 16, 0, 0);
}

// ---- f32 staging: wave wv stages plane wv, 3 rows; one gll16 covers 256 floats
__device__ __forceinline__ void stage_f32(float* buf, const float* src,
                                          const float* zrow, int h, int t) {
    const int wv = t >> 6, lane = t & 63;
#pragma unroll
    for (int r = 0; r < 3; r++) {
        int gh = h + r - 1;
        const float* rp = ((unsigned)gh < Hh) ? (src + (size_t)wv * HW + (size_t)gh * Ww) : zrow;
        gll16(rp + lane * 4, buf + (wv * 3 + r) * TR + 4);
    }
}

// ---- compute one CHUNK of input channels (f32 tile, interior at slot gw+4) ----
template <int NACC>
__device__ __forceinline__ void conv_chunk_f32(const float* buf, int t,
        const float* const (&wb)[NACC], int icc, int ictot, float (&acc)[NACC][16]) {
#pragma unroll
    for (int ic = 0; ic < CHUNK; ic++) {
        float v[9];
#pragma unroll
        for (int ky = 0; ky < 3; ky++)
#pragma unroll
            for (int kx = 0; kx < 3; kx++)
                v[ky * 3 + kx] = buf[(ic * 3 + ky) * TR + t + 3 + kx];
#pragma unroll
        for (int a = 0; a < NACC; a++) {
            const float* wp = wb[a] + (size_t)(icc + ic) * 9;
#pragma unroll
            for (int oc = 0; oc < 16; oc++) {
#pragma unroll
                for (int k = 0; k < 9; k++)
                    acc[a][oc] = fmaf(v[k], wp[(size_t)oc * ictot * 9 + k], acc[a][oc]);
            }
        }
    }
}

// ---------------- MFMA A-fragment prep for gamma/beta weights --------------
// layout: [(mat*2+hl)*4 + ocb][kstep=icq*9+tap][oc16][k32] bf16; hi/lo split of fp32
__global__ void prep_wfrag(const float* __restrict__ wg, const float* __restrict__ wb2,
                           ushort* __restrict__ dst) {
    const int N = 16 * 36 * 512;   // 294912
    for (int idx = blockIdx.x * blockDim.x + threadIdx.x; idx < N; idx += gridDim.x * blockDim.x) {
        int k = idx & 31, oc = (idx >> 5) & 15;
        int blk = idx >> 9;
        int ks = blk % 36, q = blk / 36;
        int ocbI = q & 3, q4 = q >> 2, hl = q4 & 1, mat = q4 >> 1;
        int icq = ks / 9, tap = ks % 9;
        int OC = ocbI * 16 + oc, ic = icq * 32 + k;
        const float* w = mat ? wb2 : wg;
        float v = w[((size_t)OC * 128 + ic) * 9 + tap];
        __hip_bfloat16 h16 = __float2bfloat16(v);
        if (hl) { float r = v - __bfloat162float(h16); h16 = __float2bfloat16(r); }
        dst[idx] = *(ushort*)&h16;
    }
}

// ---------------- conv_sh lookup table ------------------------------------
// T[b][oc][lab*9+tap] = sum_{f<64} w_sh[oc][f][tap]*codes[b][lab][f] + w_sh[oc][64+lab][tap]
__global__ void make_T(const float* __restrict__ codes, const float* __restrict__ w_sh,
                       float* __restrict__ T) {
    __shared__ float cod[64];
    const int lab = blockIdx.x, b = blockIdx.y, t = threadIdx.x;
    if (t < 64) cod[t] = codes[((size_t)b * LABELS + lab) * SDIM + t];
    __syncthreads();
    for (int i = t; i < NHID * 9; i += 256) {
        int oc = i / 9, tap = i % 9;
        float s = w_sh[((size_t)oc * 99 + 64 + lab) * 9 + tap];
#pragma unroll
        for (int ic = 0; ic < 64; ic++)
            s = fmaf(w_sh[((size_t)oc * 99 + ic) * 9 + tap], cod[ic], s);
        T[((size_t)b * NHID + oc) * (LABELS * 9) + lab * 9 + tap] = s;
    }
}

// ---------------- fused: conv1(64->64,lrelu)+masked pooling AND conv_c0 stats
__global__ __launch_bounds__(256) void conv1c0_kernel(
    const float* __restrict__ in,
    const float* __restrict__ w1, const float* __restrict__ b1,
    const float* __restrict__ w0, const float* __restrict__ b0,
    const int* __restrict__ seg, const float* __restrict__ bg,
    const float* __restrict__ mask, const float* __restrict__ zrow,
    float* __restrict__ sums, int* __restrict__ cnts, float* __restrict__ statacc)
{
    __shared__ __align__(16) float tile[2][FSTRIDE];
    __shared__ float s35[LABELS * 16];
    __shared__ int   c35[LABELS];
    __shared__ float wsum[4][16][2];

    const int t = threadIdx.x, h = blockIdx.y, b = blockIdx.z, ocb = blockIdx.x * 16;
    for (int i = t; i < LABELS * 16; i += 256) s35[i] = 0.f;
    if (t < LABELS) c35[t] = 0;
    if (t < 48) { int bu = t / 24, rr = (t % 24) >> 1, sl = (t & 1) ? TR - 4 : 3;
                  tile[bu][rr * TR + sl] = 0.f; }

    float acc[2][16];
#pragma unroll
    for (int i = 0; i < 16; i++) { acc[0][i] = b1[ocb + i]; acc[1][i] = b0[ocb + i]; }

    const float* inb = in + (size_t)b * 64 * HW;
    const float* wb[2] = { w1 + (size_t)ocb * 64 * 9, w0 + (size_t)ocb * 64 * 9 };

    stage_f32(tile[0], inb, zrow, h, t);
    __syncthreads();
    int nb = 0;
    for (int icc = 0; icc < 64; icc += CHUNK) {
        if (icc + CHUNK < 64) stage_f32(tile[nb ^ 1], inb + (size_t)(icc + CHUNK) * HW, zrow, h, t);
        conv_chunk_f32<2>(tile[nb], t, wb, icc, 64, acc);
        __syncthreads();
        nb ^= 1;
    }

    // --- conv1 branch: lrelu + masked class pooling
    int p = h * Ww + t;
    int lab = seg[(size_t)b * HW + p];
    bool m = (bg[(size_t)b * HW + p] != 0.f) && (mask[(size_t)b * HW + p] == 0.f);
    if (m) {
#pragma unroll
        for (int oc = 0; oc < 16; oc++) {
            float o = acc[0][oc];
            o = (o >= 0.f) ? o : 0.2f * o;
            atomicAdd(&s35[lab * 16 + oc], o);
        }
        if (blockIdx.x == 0) atomicAdd(&c35[lab], 1);
    }
    // --- conv_c0 branch: per-channel sum / sumsq
    int lane = t & 63, wv = t >> 6;
#pragma unroll
    for (int oc = 0; oc < 16; oc++) {
        float s = acc[1][oc], ss = acc[1][oc] * acc[1][oc];
#pragma unroll
        for (int off = 32; off > 0; off >>= 1) { s += __shfl_down(s, off); ss += __shfl_down(ss, off); }
        if (lane == 0) { wsum[wv][oc][0] = s; wsum[wv][oc][1] = ss; }
    }
    __syncthreads();
    for (int i = t; i < LABELS * 16; i += 256) {
        float v = s35[i];
        if (v != 0.f) {
            int s = i >> 4, oc = i & 15;
            atomicAdd(&sums[((size_t)b * LABELS + s) * SDIM + ocb + oc], v);
        }
    }
    if (blockIdx.x == 0 && t < LABELS && c35[t] > 0) atomicAdd(&cnts[b * LABELS + t], c35[t]);
    if (t < 16) {
        float S = 0.f, SS = 0.f;
#pragma unroll
        for (int w2 = 0; w2 < 4; w2++) { S += wsum[w2][t][0]; SS += wsum[w2][t][1]; }
        atomicAdd(&statacc[(size_t)(b * SDIM + ocb + t) * 2 + 0], S);
        atomicAdd(&statacc[(size_t)(b * SDIM + ocb + t) * 2 + 1], SS);
    }
}

// ---------------- codes = keep * where(cnt>0, sums/cnt, 0) ------------------
__global__ void codes_kernel(const float* __restrict__ sums, const int* __restrict__ cnts,
                             float* __restrict__ codes) {
    int idx = blockIdx.x * blockDim.x + threadIdx.x;
    if (idx >= Bn * LABELS * SDIM) return;
    int s  = (idx >> 6) % LABELS;
    int bs = idx >> 6;
    int cnt = cnts[bs];
    bool keep = !(s >= 24 && s <= 33);
    codes[idx] = (cnt > 0 && keep) ? sums[idx] / (float)cnt : 0.f;
}

__global__ void finalize_stats(const float* __restrict__ statacc,
                               float* __restrict__ mu, float* __restrict__ rsig) {
    int i = blockIdx.x * blockDim.x + threadIdx.x;
    if (i >= Bn * SDIM) return;
    float S = statacc[2 * i], SS = statacc[2 * i + 1];
    float m = S / (float)HW;
    float v = SS / (float)HW - m * m;
    mu[i] = m;
    rsig[i] = rsqrtf(v + 1e-5f);
}

// ---------------- conv_sh via per-(lab,tap) lookup table --------------------
// actv written CHANNEL-LAST [h][x][ic128] bf16, XOR swizzle in global layout
__global__ __launch_bounds__(256) void conv_sh_kernel(
    const int* __restrict__ seg, const float* __restrict__ bg,
    const float* __restrict__ T, const float* __restrict__ bf,
    __hip_bfloat16* __restrict__ actv, int b0, int abstride)
{
    __shared__ float Ts[16 * 316];        // oc stride 316 (= 315 + 1 pad)
    __shared__ int   labr[3 * 260];
    __shared__ float bgr[3 * 260];

    const int t = threadIdx.x, h = blockIdx.y, bxI = blockIdx.x, ocb = bxI * 16;
    const int b = b0 + blockIdx.z;
    const int*   seg_b = seg + (size_t)b * HW;
    const float* bg_b  = bg + (size_t)b * HW;
    __hip_bfloat16* actv_b = actv + (size_t)blockIdx.z * abstride;

    // load T slice for this oc-block: rows contiguous in global
    const float* Tb = T + ((size_t)b * NHID + ocb) * 315;
    for (int i = t; i < 16 * 315; i += 256)
        Ts[(i / 315) * 316 + (i % 315)] = Tb[i];

    // halo rows of lab/bg
    for (int i = t; i < 3 * 258; i += 256) {
        int r = i / 258, x = i % 258;
        int gh = h + r - 1, gw = x - 1;
        int lab = 0; float bgv = 0.f;
        if ((unsigned)gh < Hh && (unsigned)gw < Ww) { lab = seg_b[gh * Ww + gw]; bgv = bg_b[gh * Ww + gw]; }
        labr[r * 260 + x] = lab; bgr[r * 260 + x] = bgv;
    }

    float acc[16];
#pragma unroll
    for (int oc = 0; oc < 16; oc++) acc[oc] = bf[ocb + oc];
    __syncthreads();

#pragma unroll
    for (int ky = 0; ky < 3; ky++) {
#pragma unroll
        for (int kx = 0; kx < 3; kx++) {
            int lab  = labr[ky * 260 + t + kx];
            float bgv = bgr[ky * 260 + t + kx];
            int off = lab * 9 + ky * 3 + kx;
#pragma unroll
            for (int oc = 0; oc < 16; oc++)
                acc[oc] = fmaf(Ts[oc * 316 + off], bgv, acc[oc]);
        }
    }

    // relu + pack 16 oc -> two swizzled 16B units of channel-last cell (h, x=t)
    int x = t;
    int s = (x ^ (x >> 2)) & 3;
    int quarter = bxI >> 1;            // ic-quarter (32-ch group) these oc land in
    int m0 = (bxI & 1) * 2;            // logical 16B-unit index within quarter
    uint pk[8];
#pragma unroll
    for (int i = 0; i < 8; i++) {
        float lo = fmaxf(acc[2 * i], 0.f), hi = fmaxf(acc[2 * i + 1], 0.f);
        __hip_bfloat16 l16 = __float2bfloat16(lo), h16 = __float2bfloat16(hi);
        pk[i] = (uint)*(ushort*)&l16 | ((uint)*(ushort*)&h16 << 16);
    }
    char* cell = (char*)actv_b + (((size_t)h * 256 + x) << 8) + (quarter << 6);
    *(uint4*)(cell + (((m0 + 0) ^ s) << 4)) = make_uint4(pk[0], pk[1], pk[2], pk[3]);
    *(uint4*)(cell + (((m0 + 1) ^ s) << 4)) = make_uint4(pk[4], pk[5], pk[6], pk[7]);
}

// ---------------- fused: dx=conv_c0 (VALU) + gamma/beta convs (MFMA) + IN + lrelu
__global__ __launch_bounds__(256) void final_fused_kernel(
    const float* __restrict__ fin, const __hip_bfloat16* __restrict__ actv,
    const float* __restrict__ wc0, const float* __restrict__ bc0,
    const ushort* __restrict__ wfrag,
    const float* __restrict__ bg2, const float* __restrict__ bb2,
    const float* __restrict__ mu, const float* __restrict__ rsig,
    const float* __restrict__ zrow, float* __restrict__ out, int b0, int abstride)
{
    __shared__ __align__(16) char smem[49536];
    const int t = threadIdx.x, h = blockIdx.y, bxI = blockIdx.x, ocb = bxI * 16;
    const int b = b0 + blockIdx.z;
    const int l = t & 63, wv = t >> 6;
    const float* fin_b = fin + (size_t)b * 64 * HW;
    const char* actv_b = (const char*)(actv + (size_t)blockIdx.z * abstride);

    // ---- pass 1: dx = conv_c0(featmap_in), fp32 VALU, double-buffered ----
    float* tf = (float*)smem;
    if (t < 48) { int bu = t / 24, rr = (t % 24) >> 1, sl = (t & 1) ? TR - 4 : 3;
                  tf[bu * FSTRIDE + rr * TR + sl] = 0.f; }
    float accd[1][16];
#pragma unroll
    for (int i = 0; i < 16; i++) accd[0][i] = bc0[ocb + i];
    const float* wbd[1] = { wc0 + (size_t)ocb * 64 * 9 };

    stage_f32(tf, fin_b, zrow, h, t);
    __syncthreads();
    int nb = 0;
    for (int icc = 0; icc < 64; icc += CHUNK) {
        if (icc + CHUNK < 64) stage_f32(tf + (nb ^ 1) * FSTRIDE, fin_b + (size_t)(icc + CHUNK) * HW, zrow, h, t);
        conv_chunk_f32<1>(tf + nb * FSTRIDE, t, wbd, icc, 64, accd);
        __syncthreads();
        nb ^= 1;
    }

    // ---- pass 2: gamma/beta via MFMA over channel-last bf16 actv ----
    // LDS tile: [3 rows][258 x-cells][4 units of 8 ic] bf16x8, single-buffered
    bf16x8* tileB = (bf16x8*)smem;
    if (t < 24) { int rr = t >> 3, half = (t >> 2) & 1, u = t & 3;
        bf16x8 z = {0, 0, 0, 0, 0, 0, 0, 0};
        tileB[(rr * 258 + (half ? 257 : 0)) * 4 + u] = z; }

    f32x4 accg[4], accb[4];
#pragma unroll
    for (int j = 0; j < 4; j++) {
        int c = ocb + ((l >> 4) << 2) + j;
        float vg = bg2[c], vb = bb2[c];
#pragma unroll
        for (int pt = 0; pt < 4; pt++) { accg[pt][j] = vg; accb[pt][j] = vb; }
    }

    const char* wfA = (const char*)wfrag;
    const int loff = ((l & 15) << 6) + ((l >> 4) << 4);   // A-frag lane byte offset

    for (int icq = 0; icq < 4; icq++) {
        // stage 32-ic chunk: 48 gll16 split over 4 waves (linear dest, swizzle in global)
#pragma unroll
        for (int i = 0; i < 12; i++) {
            int k = wv * 12 + i;
            int r = k >> 4;
            int n = ((k & 15) << 6) + l;
            int gh = h + r - 1;
            const char* src = ((unsigned)gh < Hh)
                ? actv_b + (((size_t)gh * 256 + (n >> 2)) << 8) + (icq << 6) + ((n & 3) << 4)
                : (const char*)zrow + (l << 4);
            gll16(src, &tileB[((r * 258 + 1) << 2) + ((k & 15) << 6)]);
        }
        __syncthreads();
#pragma unroll
        for (int tap = 0; tap < 9; tap++) {
            const int ky = tap / 3, kx = tap % 3;
            const int ks = icq * 9 + tap;
            const bf16x8 agh = *(const bf16x8*)(wfA + ((size_t)(((0 * 4 + bxI) * 36 + ks)) << 10) + loff);
            const bf16x8 agl = *(const bf16x8*)(wfA + ((size_t)(((1 * 4 + bxI) * 36 + ks)) << 10) + loff);
            const bf16x8 abh = *(const bf16x8*)(wfA + ((size_t)(((2 * 4 + bxI) * 36 + ks)) << 10) + loff);
            const bf16x8 abl = *(const bf16x8*)(wfA + ((size_t)(((3 * 4 + bxI) * 36 + ks)) << 10) + loff);
#pragma unroll
            for (int pt = 0; pt < 4; pt++) {
                int xs = (wv << 6) + (pt << 4) + (l & 15) + kx;
                int gm = xs - 1;
                int gph = (l >> 4) ^ ((gm ^ (gm >> 2)) & 3);
                bf16x8 bfr = tileB[((ky * 258 + xs) << 2) + gph];
                accg[pt] = __builtin_amdgcn_mfma_f32_16x16x32_bf16(agh, bfr, accg[pt], 0, 0, 0);
                accg[pt] = __builtin_amdgcn_mfma_f32_16x16x32_bf16(agl, bfr, accg[pt], 0, 0, 0);
                accb[pt] = __builtin_amdgcn_mfma_f32_16x16x32_bf16(abh, bfr, accb[pt], 0, 0, 0);
                accb[pt] = __builtin_amdgcn_mfma_f32_16x16x32_bf16(abl, bfr, accb[pt], 0, 0, 0);
            }
        }
        __syncthreads();
    }

    // ---- epilogue: hand dx across lanes via LDS (stride 260 = 2-way free) ----
    float* dxl = (float*)smem;
#pragma unroll
    for (int oc = 0; oc < 16; oc++) dxl[oc * 260 + t] = accd[0][oc];
    __syncthreads();

    const float* mu_b = mu + b * SDIM;
    const float* rs_b = rsig + b * SDIM;
    float* out_b = out + (size_t)b * SDIM * HW;
    float muj[4], rsj[4];
#pragma unroll
    for (int j = 0; j < 4; j++) { int c = ocb + ((l >> 4) << 2) + j; muj[j] = mu_b[c]; rsj[j] = rs_b[c]; }
#pragma unroll
    for (int pt = 0; pt < 4; pt++) {
        int px = (wv << 6) + (pt << 4) + (l & 15);
#pragma unroll
        for (int j = 0; j < 4; j++) {
            int cl = ((l >> 4) << 2) + j;
            float nrm = (dxl[cl * 260 + px] - muj[j]) * rsj[j];
            float o = nrm * (1.f + accg[pt][j]) + accb[pt][j];
            o = (o >= 0.f) ? o : 0.2f * o;
            out_b[(size_t)(ocb + cl) * HW + h * Ww + px] = o;
        }
    }
}

// ===========================================================================
extern "C" void kernel_launch(void* const* d_in, const int* in_sizes, int n_in,
                              void* d_out, int out_size, void* d_ws, size_t ws_size,
                              hipStream_t stream) {
    const float* featmap_in = (const float*)d_in[0];
    const int*   seg        = (const int*)d_in[1];
    const float* bg         = (const float*)d_in[2];
    const float* mask       = (const float*)d_in[3];
    const float* w_conv     = (const float*)d_in[4];
    const float* b_conv     = (const float*)d_in[5];
    const float* w_c0       = (const float*)d_in[6];
    const float* b_c0       = (const float*)d_in[7];
    const float* w_sh       = (const float*)d_in[8];
    const float* b_sh       = (const float*)d_in[9];
    const float* w_g        = (const float*)d_in[10];
    const float* b_g        = (const float*)d_in[11];
    const float* w_b        = (const float*)d_in[12];
    const float* b_b        = (const float*)d_in[13];
    float* out = (float*)d_out;

    // ---- workspace arena ----
    char* ws = (char*)d_ws;
    size_t o = 0;
    auto alloc = [&](size_t bytes) -> char* {
        size_t r = o; o = (o + bytes + 255) & ~(size_t)255; return ws + r;
    };
    ushort* wfrag   = (ushort*)alloc((size_t)16 * 36 * 512 * 2);   // 589824 B
    float*  Ttab    = (float*)alloc((size_t)Bn * NHID * LABELS * 9 * 4);  // 1.61 MB
    float*  sums    = (float*)alloc((size_t)Bn * LABELS * SDIM * 4);
    int*    cnts    = (int*)alloc((size_t)Bn * LABELS * 4);
    float*  codes   = (float*)alloc((size_t)Bn * LABELS * SDIM * 4);
    float*  statacc = (float*)alloc((size_t)Bn * SDIM * 2 * 4);
    float*  mu      = (float*)alloc((size_t)Bn * SDIM * 4);
    float*  rsig    = (float*)alloc((size_t)Bn * SDIM * 4);
    float*  zrow    = (float*)alloc(256 * 4);            // 1 KB zero row (OOB source)
    size_t actv_full = (size_t)Bn * NHID * HW * 2;       // 134 MB (bf16, all batches)
    size_t actv_one  = (size_t)NHID * HW * 2;            // 16.8 MB
    bool batched = (ws_size > o) && ((ws_size - o) >= actv_full + 512);
    __hip_bfloat16* actv = (__hip_bfloat16*)alloc(batched ? actv_full : actv_one);

    prep_wfrag<<<288, 256, 0, stream>>>(w_g, w_b, wfrag);

    hipMemsetAsync(sums, 0, (size_t)Bn * LABELS * SDIM * 4, stream);
    hipMemsetAsync(cnts, 0, (size_t)Bn * LABELS * 4, stream);
    hipMemsetAsync(statacc, 0, (size_t)Bn * SDIM * 2 * 4, stream);
    hipMemsetAsync(zrow, 0, 256 * 4, stream);

    conv1c0_kernel<<<dim3(4, Hh, Bn), 256, 0, stream>>>(
        featmap_in, w_conv, b_conv, w_c0, b_c0, seg, bg, mask, zrow, sums, cnts, statacc);
    codes_kernel<<<(Bn * LABELS * SDIM + 255) / 256, 256, 0, stream>>>(sums, cnts, codes);
    finalize_stats<<<2, 256, 0, stream>>>(statacc, mu, rsig);
    make_T<<<dim3(LABELS, Bn), 256, 0, stream>>>(codes, w_sh, Ttab);

    if (batched) {
        conv_sh_kernel<<<dim3(8, Hh, Bn), 256, 0, stream>>>(
            seg, bg, Ttab, b_sh, actv, 0, NHID * HW);
        final_fused_kernel<<<dim3(4, Hh, Bn), 256, 0, stream>>>(
            featmap_in, actv, w_c0, b_c0, wfrag, b_g, b_b, mu, rsig, zrow, out, 0, NHID * HW);
    } else {
        for (int b = 0; b < Bn; b++) {
            conv_sh_kernel<<<dim3(8, Hh, 1), 256, 0, stream>>>(
                seg, bg, Ttab, b_sh, actv, b, 0);
            final_fused_kernel<<<dim3(4, Hh, 1), 256, 0, stream>>>(
                featmap_in, actv, w_c0, b_c0, wfrag, b_g, b_b, mu, rsig, zrow, out, b, 0);
        }
    }
}

// Round 7
// 1511.079 us; speedup vs baseline: 19.3112x; 2.1055x over previous
//
#include <hip/hip_runtime.h>
#include <hip/hip_bf16.h>
#include <cstdint>

#define Bn 8
#define Hh 256
#define Ww 256
#define HW 65536
#define SDIM 64
#define LABELS 35
#define NHID 128
// channel-last tensor: [h][octet(16)][px(256)] of 16B units; bytes per batch:
#define CLB ((size_t)Hh * 16 * 256 * 16)

typedef __attribute__((ext_vector_type(8))) short bf16x8;   // 8 bf16 = one A/B k-octet
typedef __attribute__((ext_vector_type(4))) float f32x4;    // MFMA C/D frag
#define MFMA16 __builtin_amdgcn_mfma_f32_16x16x32_bf16

// ---- async global->LDS 16B copy: dest = wave-uniform base + lane*16, src per-lane
__device__ __forceinline__ void gll16(const void* g, void* l) {
    __builtin_amdgcn_global_load_lds(
        (__attribute__((address_space(1))) const void*)(uintptr_t)g,
        (__attribute__((address_space(3))) void*)(uint32_t)(uintptr_t)l, 16, 0, 0);
}

// ---- LDS tile for one 32-ch group: bf16x8 [3 rows][4 octet-slots][260 px-slots]
// px-slot p holds input px = p-1 (slots 0 and 257 are persistent zeros = conv pad).
#define TUNITS (3 * 4 * 260)

// stage one 32-ch group (octets jo0..jo0+3) of a CL tensor into the tile
__device__ __forceinline__ void stageCL(bf16x8* tile, const char* clb, int jo0,
                                        int h, int t, const float* zrow) {
    const int wv = t >> 6, l = t & 63;
#pragma unroll
    for (int i = 0; i < 12; i++) {
        int k = wv * 12 + i;                 // 0..47
        int r = k >> 4, rem = k & 15, s = rem >> 2, q = rem & 3;
        int gh = h + r - 1;
        const char* src = ((unsigned)gh < Hh)
            ? clb + ((((size_t)gh * 16 + jo0 + s) * 256) + (size_t)q * 64 + l) * 16
            : (const char*)zrow + l * 16;
        gll16(src, tile + (r * 4 + s) * 260 + 1 + q * 64);
    }
}

// B-fragment read: lane l -> octet-slot l>>4, px = wv*64+pt*16+(l&15)+kx-1 (slot +kx)
__device__ __forceinline__ bf16x8 bread(const bf16x8* tile, int ky, int kx,
                                        int pt, int wv, int l) {
    return tile[(ky * 4 + (l >> 4)) * 260 + wv * 64 + pt * 16 + (l & 15) + kx];
}

__device__ __forceinline__ bf16x8 aread(const ushort* base, int blk, int loff) {
    return *(const bf16x8*)((const char*)base + ((size_t)blk << 10) + loff);
}
// wfC block index: mats 0=w1hi 1=w1lo 2=w0hi 3=w0lo ; half = ic-half (0:0-31,1:32-63)
__device__ __forceinline__ int blkC(int ocbI, int mat, int half, int tap) {
    return (((ocbI * 4 + mat) * 2 + half) * 9 + tap);
}

// ---------------- repack: fin fp32 [b][ic][h][w] -> finCL hi/lo bf16 ---------
__global__ __launch_bounds__(256) void repack_fin(
    const float* __restrict__ fin, char* __restrict__ fincl, int batch0)
{
    __shared__ __align__(16) float fs[64 * 256];
    const int t = threadIdx.x, h = blockIdx.x, z = blockIdx.y;
    const int b = batch0 + z;
    const int wv = t >> 6, l = t & 63;
    const float* finb = fin + (size_t)b * 64 * HW + (size_t)h * 256;
#pragma unroll
    for (int i = 0; i < 16; i++) {
        int ic = wv * 16 + i;
        gll16(finb + (size_t)ic * HW + l * 4, fs + ic * 256);
    }
    __syncthreads();
    char* outb = fincl + (size_t)z * CLB + (size_t)h * 16 * 256 * 16;
#pragma unroll
    for (int jo = 0; jo < 8; jo++) {
        uint hi[4], lo[4];
#pragma unroll
        for (int c = 0; c < 8; c += 2) {
            float v0 = fs[(jo * 8 + c) * 256 + t];
            float v1 = fs[(jo * 8 + c + 1) * 256 + t];
            __hip_bfloat16 h0 = __float2bfloat16(v0), h1 = __float2bfloat16(v1);
            float r0 = v0 - __bfloat162float(h0), r1 = v1 - __bfloat162float(h1);
            __hip_bfloat16 l0 = __float2bfloat16(r0), l1 = __float2bfloat16(r1);
            hi[c >> 1] = (uint)*(ushort*)&h0 | ((uint)*(ushort*)&h1 << 16);
            lo[c >> 1] = (uint)*(ushort*)&l0 | ((uint)*(ushort*)&l1 << 16);
        }
        *(uint4*)(outb + ((size_t)jo * 256 + t) * 16)       = make_uint4(hi[0], hi[1], hi[2], hi[3]);
        *(uint4*)(outb + ((size_t)(jo + 8) * 256 + t) * 16) = make_uint4(lo[0], lo[1], lo[2], lo[3]);
    }
}

// ---------------- A-frag prep for w1 (w_conv) and w0 (w_c0), hi/lo ----------
// dst blocks of 512 elems [oc16][k32]: blk = ((ocbI*4 + mat)*2 + half)*9 + tap
__global__ void prep_wfragC(const float* __restrict__ w1, const float* __restrict__ w0,
                            ushort* __restrict__ dst) {
    const int N = 288 * 512;
    for (int idx = blockIdx.x * blockDim.x + threadIdx.x; idx < N; idx += gridDim.x * blockDim.x) {
        int k = idx & 31, oc = (idx >> 5) & 15;
        int blk = idx >> 9;
        int tap = blk % 9, r = blk / 9;
        int half = r & 1; r >>= 1;
        int mat = r & 3; int ocbI = r >> 2;
        int OC = ocbI * 16 + oc, ic = half * 32 + k;
        const float* w = (mat < 2) ? w1 : w0;
        float v = w[((size_t)OC * 64 + ic) * 9 + tap];
        __hip_bfloat16 h16 = __float2bfloat16(v);
        if (mat & 1) { float rr = v - __bfloat162float(h16); h16 = __float2bfloat16(rr); }
        dst[idx] = *(ushort*)&h16;
    }
}

// ---------------- A-frag prep for gamma/beta (verified round-5 layout) ------
// blk = ((mat*2+hl)*4 + ocbI)*36 + icq*9 + tap ; mat 0=gamma 1=beta
__global__ void prep_wfrag(const float* __restrict__ wg, const float* __restrict__ wb2,
                           ushort* __restrict__ dst) {
    const int N = 16 * 36 * 512;
    for (int idx = blockIdx.x * blockDim.x + threadIdx.x; idx < N; idx += gridDim.x * blockDim.x) {
        int k = idx & 31, oc = (idx >> 5) & 15;
        int blk = idx >> 9;
        int ks = blk % 36, q = blk / 36;
        int ocbI = q & 3, q4 = q >> 2, hl = q4 & 1, mat = q4 >> 1;
        int icq = ks / 9, tap = ks % 9;
        int OC = ocbI * 16 + oc, ic = icq * 32 + k;
        const float* w = mat ? wb2 : wg;
        float v = w[((size_t)OC * 128 + ic) * 9 + tap];
        __hip_bfloat16 h16 = __float2bfloat16(v);
        if (hl) { float r = v - __bfloat162float(h16); h16 = __float2bfloat16(r); }
        dst[idx] = *(ushort*)&h16;
    }
}

// ---------------- fused MFMA: conv1(lrelu+pool) AND conv_c0 stats -----------
__global__ __launch_bounds__(256) void conv1c0_kernel(
    const char* __restrict__ fincl, const ushort* __restrict__ wfC,
    const float* __restrict__ bias1, const float* __restrict__ bias0,
    const int* __restrict__ seg, const float* __restrict__ bg,
    const float* __restrict__ mask, const float* __restrict__ zrow,
    float* __restrict__ sums, int* __restrict__ cnts, float* __restrict__ statacc,
    int batch0)
{
    __shared__ __align__(16) bf16x8 tile[TUNITS];
    __shared__ float s35[LABELS * 16];
    __shared__ int   c35[LABELS];
    __shared__ float wsum[4][16][2];

    const int t = threadIdx.x, h = blockIdx.y, bxI = blockIdx.x, ocb = bxI * 16;
    const int z = blockIdx.z, b = batch0 + z;
    const int l = t & 63, wv = t >> 6;
    const char* clb = fincl + (size_t)z * CLB;
    const int loff = ((l & 15) << 6) + ((l >> 4) << 4);

    for (int i = t; i < LABELS * 16; i += 256) s35[i] = 0.f;
    if (t < LABELS) c35[t] = 0;
    if (t < 24) { int r = t >> 3, s = (t >> 1) & 3, e = t & 1;
        bf16x8 zz = {0,0,0,0,0,0,0,0};
        tile[(r * 4 + s) * 260 + (e ? 257 : 0)] = zz; }

    f32x4 a1[4], a0[4];
#pragma unroll
    for (int j = 0; j < 4; j++) {
        int c = ocb + ((l >> 4) << 2) + j;
        float v1 = bias1[c], v0 = bias0[c];
#pragma unroll
        for (int pt = 0; pt < 4; pt++) { a1[pt][j] = v1; a0[pt][j] = v0; }
    }

#pragma unroll
    for (int icq = 0; icq < 4; icq++) {
        stageCL(tile, clb, icq * 4, h, t, zrow);
        __syncthreads();
#pragma unroll
        for (int tap = 0; tap < 9; tap++) {
            const int ky = tap / 3, kx = tap % 3;
            if (icq < 2) {
                bf16x8 A0 = aread(wfC, blkC(bxI, 0, icq, tap), loff);   // w1 hi
                bf16x8 A1 = aread(wfC, blkC(bxI, 1, icq, tap), loff);   // w1 lo
                bf16x8 A2 = aread(wfC, blkC(bxI, 2, icq, tap), loff);   // w0 hi
                bf16x8 A3 = aread(wfC, blkC(bxI, 3, icq, tap), loff);   // w0 lo
#pragma unroll
                for (int pt = 0; pt < 4; pt++) {
                    bf16x8 B = bread(tile, ky, kx, pt, wv, l);
                    a1[pt] = MFMA16(A0, B, a1[pt], 0, 0, 0);
                    a1[pt] = MFMA16(A1, B, a1[pt], 0, 0, 0);
                    a0[pt] = MFMA16(A2, B, a0[pt], 0, 0, 0);
                    a0[pt] = MFMA16(A3, B, a0[pt], 0, 0, 0);
                }
            } else {
                bf16x8 A0 = aread(wfC, blkC(bxI, 0, icq - 2, tap), loff); // w1 hi on lo-chs
                bf16x8 A2 = aread(wfC, blkC(bxI, 2, icq - 2, tap), loff); // w0 hi on lo-chs
#pragma unroll
                for (int pt = 0; pt < 4; pt++) {
                    bf16x8 B = bread(tile, ky, kx, pt, wv, l);
                    a1[pt] = MFMA16(A0, B, a1[pt], 0, 0, 0);
                    a0[pt] = MFMA16(A2, B, a0[pt], 0, 0, 0);
                }
            }
        }
        __syncthreads();
    }

    // ---- conv1 branch: lrelu + masked class pooling (C-layout: px=l&15 base) ----
    // NOTE: each pixel is held by the 4 lanes sharing l&15 (one per oc-group l>>4);
    // sums get one lane per (px,oc) but the COUNT must be gated to one lane (l<16).
    const int*   segh = seg  + (size_t)b * HW + (size_t)h * 256;
    const float* bgh  = bg   + (size_t)b * HW + (size_t)h * 256;
    const float* mh   = mask + (size_t)b * HW + (size_t)h * 256;
#pragma unroll
    for (int pt = 0; pt < 4; pt++) {
        int px = wv * 64 + pt * 16 + (l & 15);
        int lab = segh[px];
        bool m = (bgh[px] != 0.f) && (mh[px] == 0.f);
        if (m) {
#pragma unroll
            for (int j = 0; j < 4; j++) {
                float o = a1[pt][j];
                o = (o >= 0.f) ? o : 0.2f * o;
                atomicAdd(&s35[lab * 16 + ((l >> 4) << 2) + j], o);
            }
            if (bxI == 0 && l < 16) atomicAdd(&c35[lab], 1);
        }
    }
    // ---- conv_c0 branch: per-channel sum / sumsq ----
#pragma unroll
    for (int j = 0; j < 4; j++) {
        float s = a0[0][j] + a0[1][j] + a0[2][j] + a0[3][j];
        float ss = a0[0][j]*a0[0][j] + a0[1][j]*a0[1][j] + a0[2][j]*a0[2][j] + a0[3][j]*a0[3][j];
#pragma unroll
        for (int off = 1; off < 16; off <<= 1) { s += __shfl_xor(s, off); ss += __shfl_xor(ss, off); }
        if ((l & 15) == 0) { wsum[wv][((l >> 4) << 2) + j][0] = s; wsum[wv][((l >> 4) << 2) + j][1] = ss; }
    }
    __syncthreads();
    for (int i = t; i < LABELS * 16; i += 256) {
        float v = s35[i];
        if (v != 0.f) {
            int s = i >> 4, oc = i & 15;
            atomicAdd(&sums[((size_t)b * LABELS + s) * SDIM + ocb + oc], v);
        }
    }
    if (bxI == 0 && t < LABELS && c35[t] > 0) atomicAdd(&cnts[b * LABELS + t], c35[t]);
    if (t < 16) {
        float S = 0.f, SS = 0.f;
#pragma unroll
        for (int w2 = 0; w2 < 4; w2++) { S += wsum[w2][t][0]; SS += wsum[w2][t][1]; }
        atomicAdd(&statacc[(size_t)(b * SDIM + ocb + t) * 2 + 0], S);
        atomicAdd(&statacc[(size_t)(b * SDIM + ocb + t) * 2 + 1], SS);
    }
}

// ---------------- codes = keep * where(cnt>0, sums/cnt, 0) ------------------
__global__ void codes_kernel(const float* __restrict__ sums, const int* __restrict__ cnts,
                             float* __restrict__ codes) {
    int idx = blockIdx.x * blockDim.x + threadIdx.x;
    if (idx >= Bn * LABELS * SDIM) return;
    int s  = (idx >> 6) % LABELS;
    int bs = idx >> 6;
    int cnt = cnts[bs];
    bool keep = !(s >= 24 && s <= 33);
    codes[idx] = (cnt > 0 && keep) ? sums[idx] / (float)cnt : 0.f;
}

__global__ void finalize_stats(const float* __restrict__ statacc,
                               float* __restrict__ mu, float* __restrict__ rsig) {
    int i = blockIdx.x * blockDim.x + threadIdx.x;
    if (i >= Bn * SDIM) return;
    float S = statacc[2 * i], SS = statacc[2 * i + 1];
    float m = S / (float)HW;
    float v = SS / (float)HW - m * m;
    mu[i] = m;
    rsig[i] = rsqrtf(v + 1e-5f);
}

// ---------------- conv_sh lookup table ------------------------------------
__global__ void make_T(const float* __restrict__ codes, const float* __restrict__ w_sh,
                       float* __restrict__ T) {
    __shared__ float cod[64];
    const int lab = blockIdx.x, b = blockIdx.y, t = threadIdx.x;
    if (t < 64) cod[t] = codes[((size_t)b * LABELS + lab) * SDIM + t];
    __syncthreads();
    for (int i = t; i < NHID * 9; i += 256) {
        int oc = i / 9, tap = i % 9;
        float s = w_sh[((size_t)oc * 99 + 64 + lab) * 9 + tap];
#pragma unroll
        for (int ic = 0; ic < 64; ic++)
            s = fmaf(w_sh[((size_t)oc * 99 + ic) * 9 + tap], cod[ic], s);
        T[((size_t)b * NHID + oc) * (LABELS * 9) + lab * 9 + tap] = s;
    }
}

// ---------------- conv_sh via T-table; actv plane layout [h][oct][px] -------
__global__ __launch_bounds__(256) void conv_sh_kernel(
    const int* __restrict__ seg, const float* __restrict__ bg,
    const float* __restrict__ T, const float* __restrict__ bf,
    char* __restrict__ actv, int batch0)
{
    __shared__ float Ts[16 * 316];
    __shared__ int   labr[3 * 260];
    __shared__ float bgr[3 * 260];

    const int t = threadIdx.x, h = blockIdx.y, bxI = blockIdx.x, ocb = bxI * 16;
    const int z = blockIdx.z, b = batch0 + z;
    const int*   seg_b = seg + (size_t)b * HW;
    const float* bg_b  = bg + (size_t)b * HW;
    char* actv_b = actv + (size_t)z * CLB;

    const float* Tb = T + ((size_t)b * NHID + ocb) * 315;
    for (int i = t; i < 16 * 315; i += 256)
        Ts[(i / 315) * 316 + (i % 315)] = Tb[i];

    for (int i = t; i < 3 * 258; i += 256) {
        int r = i / 258, x = i % 258;
        int gh = h + r - 1, gw = x - 1;
        int lab = 0; float bgv = 0.f;
        if ((unsigned)gh < Hh && (unsigned)gw < Ww) { lab = seg_b[gh * Ww + gw]; bgv = bg_b[gh * Ww + gw]; }
        labr[r * 260 + x] = lab; bgr[r * 260 + x] = bgv;
    }

    float acc[16];
#pragma unroll
    for (int oc = 0; oc < 16; oc++) acc[oc] = bf[ocb + oc];
    __syncthreads();

#pragma unroll
    for (int ky = 0; ky < 3; ky++) {
#pragma unroll
        for (int kx = 0; kx < 3; kx++) {
            int lab  = labr[ky * 260 + t + kx];
            float bgv = bgr[ky * 260 + t + kx];
            int off = lab * 9 + ky * 3 + kx;
#pragma unroll
            for (int oc = 0; oc < 16; oc++)
                acc[oc] = fmaf(Ts[oc * 316 + off], bgv, acc[oc]);
        }
    }

    // relu + pack 16 oc -> octets 2*bxI, 2*bxI+1 at px=t (coalesced 16B stores)
    uint pk[8];
#pragma unroll
    for (int i = 0; i < 8; i++) {
        float lo = fmaxf(acc[2 * i], 0.f), hi = fmaxf(acc[2 * i + 1], 0.f);
        __hip_bfloat16 l16 = __float2bfloat16(lo), h16 = __float2bfloat16(hi);
        pk[i] = (uint)*(ushort*)&l16 | ((uint)*(ushort*)&h16 << 16);
    }
    *(uint4*)(actv_b + (((size_t)h * 16 + bxI * 2)     * 256 + t) * 16) = make_uint4(pk[0], pk[1], pk[2], pk[3]);
    *(uint4*)(actv_b + (((size_t)h * 16 + bxI * 2 + 1) * 256 + t) * 16) = make_uint4(pk[4], pk[5], pk[6], pk[7]);
}

// ---------------- fused: dx (MFMA over finCL) + gamma/beta (MFMA) + IN + lrelu
__global__ __launch_bounds__(256) void final_fused_kernel(
    const char* __restrict__ fincl, const char* __restrict__ actv,
    const ushort* __restrict__ wfC, const ushort* __restrict__ wfGB,
    const float* __restrict__ bc0, const float* __restrict__ bg2, const float* __restrict__ bb2,
    const float* __restrict__ mu, const float* __restrict__ rsig,
    const float* __restrict__ zrow, float* __restrict__ out, int batch0)
{
    __shared__ __align__(16) bf16x8 tile[TUNITS];
    const int t = threadIdx.x, h = blockIdx.y, bxI = blockIdx.x, ocb = bxI * 16;
    const int z = blockIdx.z, b = batch0 + z;
    const int l = t & 63, wv = t >> 6;
    const char* clb = fincl + (size_t)z * CLB;
    const char* avb = actv + (size_t)z * CLB;
    const int loff = ((l & 15) << 6) + ((l >> 4) << 4);

    if (t < 24) { int r = t >> 3, s = (t >> 1) & 3, e = t & 1;
        bf16x8 zz = {0,0,0,0,0,0,0,0};
        tile[(r * 4 + s) * 260 + (e ? 257 : 0)] = zz; }

    f32x4 ad[4], ag[4], ab2[4];
#pragma unroll
    for (int j = 0; j < 4; j++) {
        int c = ocb + ((l >> 4) << 2) + j;
        float vd = bc0[c], vg = bg2[c], vb = bb2[c];
#pragma unroll
        for (int pt = 0; pt < 4; pt++) { ad[pt][j] = vd; ag[pt][j] = vg; ab2[pt][j] = vb; }
    }

#pragma unroll
    for (int c8 = 0; c8 < 8; c8++) {
        const bool isfin = (c8 < 4);
        const int icq = isfin ? c8 : c8 - 4;
        stageCL(tile, isfin ? clb : avb, icq * 4, h, t, zrow);
        __syncthreads();
#pragma unroll
        for (int tap = 0; tap < 9; tap++) {
            const int ky = tap / 3, kx = tap % 3;
            if (isfin) {
                if (icq < 2) {
                    bf16x8 A2 = aread(wfC, blkC(bxI, 2, icq, tap), loff);
                    bf16x8 A3 = aread(wfC, blkC(bxI, 3, icq, tap), loff);
#pragma unroll
                    for (int pt = 0; pt < 4; pt++) {
                        bf16x8 B = bread(tile, ky, kx, pt, wv, l);
                        ad[pt] = MFMA16(A2, B, ad[pt], 0, 0, 0);
                        ad[pt] = MFMA16(A3, B, ad[pt], 0, 0, 0);
                    }
                } else {
                    bf16x8 A2 = aread(wfC, blkC(bxI, 2, icq - 2, tap), loff);
#pragma unroll
                    for (int pt = 0; pt < 4; pt++) {
                        bf16x8 B = bread(tile, ky, kx, pt, wv, l);
                        ad[pt] = MFMA16(A2, B, ad[pt], 0, 0, 0);
                    }
                }
            } else {
                const int ks = icq * 9 + tap;
                bf16x8 agh = aread(wfGB, (0 * 4 + bxI) * 36 + ks, loff);
                bf16x8 agl = aread(wfGB, (1 * 4 + bxI) * 36 + ks, loff);
                bf16x8 abh = aread(wfGB, (2 * 4 + bxI) * 36 + ks, loff);
                bf16x8 abl = aread(wfGB, (3 * 4 + bxI) * 36 + ks, loff);
#pragma unroll
                for (int pt = 0; pt < 4; pt++) {
                    bf16x8 B = bread(tile, ky, kx, pt, wv, l);
                    ag[pt]  = MFMA16(agh, B, ag[pt], 0, 0, 0);
                    ag[pt]  = MFMA16(agl, B, ag[pt], 0, 0, 0);
                    ab2[pt] = MFMA16(abh, B, ab2[pt], 0, 0, 0);
                    ab2[pt] = MFMA16(abl, B, ab2[pt], 0, 0, 0);
                }
            }
        }
        __syncthreads();
    }

    // ---- epilogue: dx already in the same C-layout as gamma/beta (no LDS bounce)
    const float* mu_b = mu + b * SDIM;
    const float* rs_b = rsig + b * SDIM;
    float* out_b = out + (size_t)b * SDIM * HW;
    float muj[4], rsj[4];
#pragma unroll
    for (int j = 0; j < 4; j++) { int c = ocb + ((l >> 4) << 2) + j; muj[j] = mu_b[c]; rsj[j] = rs_b[c]; }
#pragma unroll
    for (int pt = 0; pt < 4; pt++) {
        int px = wv * 64 + pt * 16 + (l & 15);
#pragma unroll
        for (int j = 0; j < 4; j++) {
            int cl = ((l >> 4) << 2) + j;
            float nrm = (ad[pt][j] - muj[j]) * rsj[j];
            float o = nrm * (1.f + ag[pt][j]) + ab2[pt][j];
            o = (o >= 0.f) ? o : 0.2f * o;
            out_b[(size_t)(ocb + cl) * HW + (size_t)h * 256 + px] = o;
        }
    }
}

// ===========================================================================
extern "C" void kernel_launch(void* const* d_in, const int* in_sizes, int n_in,
                              void* d_out, int out_size, void* d_ws, size_t ws_size,
                              hipStream_t stream) {
    const float* featmap_in = (const float*)d_in[0];
    const int*   seg        = (const int*)d_in[1];
    const float* bg         = (const float*)d_in[2];
    const float* mask       = (const float*)d_in[3];
    const float* w_conv     = (const float*)d_in[4];
    const float* b_conv     = (const float*)d_in[5];
    const float* w_c0       = (const float*)d_in[6];
    const float* b_c0       = (const float*)d_in[7];
    const float* w_sh       = (const float*)d_in[8];
    const float* b_sh       = (const float*)d_in[9];
    const float* w_g        = (const float*)d_in[10];
    const float* b_g        = (const float*)d_in[11];
    const float* w_b        = (const float*)d_in[12];
    const float* b_b        = (const float*)d_in[13];
    float* out = (float*)d_out;

    // ---- workspace arena ----
    char* ws = (char*)d_ws;
    size_t o = 0;
    auto alloc = [&](size_t bytes) -> char* {
        size_t r = o; o = (o + bytes + 255) & ~(size_t)255; return ws + r;
    };
    ushort* wfC     = (ushort*)alloc((size_t)288 * 512 * 2);        // 294912 B
    ushort* wfGB    = (ushort*)alloc((size_t)16 * 36 * 512 * 2);    // 589824 B
    float*  Ttab    = (float*)alloc((size_t)Bn * NHID * LABELS * 9 * 4);
    float*  sums    = (float*)alloc((size_t)Bn * LABELS * SDIM * 4);
    int*    cnts    = (int*)alloc((size_t)Bn * LABELS * 4);
    float*  codes   = (float*)alloc((size_t)Bn * LABELS * SDIM * 4);
    float*  statacc = (float*)alloc((size_t)Bn * SDIM * 2 * 4);
    float*  mu      = (float*)alloc((size_t)Bn * SDIM * 4);
    float*  rsig    = (float*)alloc((size_t)Bn * SDIM * 4);
    float*  zrow    = (float*)alloc(1024);

    size_t rem = (ws_size > o) ? ws_size - o : 0;
    int tier = (rem >= 2 * CLB * Bn + 1024) ? 1 : (rem >= CLB * Bn + CLB + 1024) ? 2 : 3;
    char* fincl; char* actvc;
    if (tier == 1)      { fincl = alloc(CLB * Bn); actvc = alloc(CLB * Bn); }
    else if (tier == 2) { fincl = alloc(CLB * Bn); actvc = alloc(CLB); }
    else                { fincl = alloc(CLB);      actvc = alloc(CLB); }

    prep_wfragC<<<144, 256, 0, stream>>>(w_conv, w_c0, wfC);
    prep_wfrag<<<288, 256, 0, stream>>>(w_g, w_b, wfGB);

    hipMemsetAsync(sums, 0, (size_t)Bn * LABELS * SDIM * 4, stream);
    hipMemsetAsync(cnts, 0, (size_t)Bn * LABELS * 4, stream);
    hipMemsetAsync(statacc, 0, (size_t)Bn * SDIM * 2 * 4, stream);
    hipMemsetAsync(zrow, 0, 1024, stream);

    if (tier <= 2) {
        repack_fin<<<dim3(Hh, Bn), 256, 0, stream>>>(featmap_in, fincl, 0);
        conv1c0_kernel<<<dim3(4, Hh, Bn), 256, 0, stream>>>(
            fincl, wfC, b_conv, b_c0, seg, bg, mask, zrow, sums, cnts, statacc, 0);
    } else {
        for (int b = 0; b < Bn; b++) {
            repack_fin<<<dim3(Hh, 1), 256, 0, stream>>>(featmap_in, fincl, b);
            conv1c0_kernel<<<dim3(4, Hh, 1), 256, 0, stream>>>(
                fincl, wfC, b_conv, b_c0, seg, bg, mask, zrow, sums, cnts, statacc, b);
        }
    }
    codes_kernel<<<(Bn * LABELS * SDIM + 255) / 256, 256, 0, stream>>>(sums, cnts, codes);
    finalize_stats<<<2, 256, 0, stream>>>(statacc, mu, rsig);
    make_T<<<dim3(LABELS, Bn), 256, 0, stream>>>(codes, w_sh, Ttab);

    if (tier == 1) {
        conv_sh_kernel<<<dim3(8, Hh, Bn), 256, 0, stream>>>(seg, bg, Ttab, b_sh, actvc, 0);
        final_fused_kernel<<<dim3(4, Hh, Bn), 256, 0, stream>>>(
            fincl, actvc, wfC, wfGB, b_c0, b_g, b_b, mu, rsig, zrow, out, 0);
    } else if (tier == 2) {
        for (int b = 0; b < Bn; b++) {
            conv_sh_kernel<<<dim3(8, Hh, 1), 256, 0, stream>>>(seg, bg, Ttab, b_sh, actvc, b);
            final_fused_kernel<<<dim3(4, Hh, 1), 256, 0, stream>>>(
                fincl + (size_t)b * CLB, actvc, wfC, wfGB, b_c0, b_g, b_b, mu, rsig, zrow, out, b);
        }
    } else {
        for (int b = 0; b < Bn; b++) {
            repack_fin<<<dim3(Hh, 1), 256, 0, stream>>>(featmap_in, fincl, b);
            conv_sh_kernel<<<dim3(8, Hh, 1), 256, 0, stream>>>(seg, bg, Ttab, b_sh, actvc, b);
            final_fused_kernel<<<dim3(4, Hh, 1), 256, 0, stream>>>(
                fincl, actvc, wfC, wfGB, b_c0, b_g, b_b, mu, rsig, zrow, out, b);
        }
    }
}